// Round 10
// baseline (569.869 us; speedup 1.0000x reference)
//
#include <hip/hip_runtime.h>
#include <hip/hip_bf16.h>

#define E_ 8
#define D_ 1024
#define F_ 4096
#define K_ 2
#define ALIGN_ 128

typedef __attribute__((ext_vector_type(8))) short short8;
typedef __attribute__((ext_vector_type(4))) float f32x4;

__device__ __forceinline__ unsigned f2bf(float f){
  union { __hip_bfloat16 h; unsigned short u; } c;
  c.h = __float2bfloat16(f);
  return (unsigned)c.u;
}

__device__ __forceinline__ float bf2f(unsigned u){
  union { float f; unsigned u; } c;
  c.u = u << 16;
  return c.f;
}

__device__ __forceinline__ float gelu_f(float v){
  const float c0 = 0.7978845608028654f;   // sqrt(2/pi)
  float z = c0 * (v + 0.044715f * v * v * v);
  float e = __expf(2.0f * z);
  float t = 1.0f - 2.0f / (1.0f + e);     // tanh(z), stable for |z| large
  return 0.5f * v * (1.0f + t);
}

__device__ __forceinline__ void gload16(const void* gsrc, void* ldst){
  __builtin_amdgcn_global_load_lds(
      (const __attribute__((address_space(1))) unsigned int*)gsrc,
      (__attribute__((address_space(3))) unsigned int*)ldst, 16, 0, 0);
}

// ---------------- gating: top-2 + softmax, no atomics, float4 loads ----------------
__global__ void gate_kernel(const float* __restrict__ x, const float* __restrict__ gw,
                            int* __restrict__ tidx, float* __restrict__ tw, int T){
  int wid = threadIdx.x >> 6, lane = threadIdx.x & 63;
  int t = blockIdx.x * 4 + wid;
  if (t >= T) return;
  const float4* xr = reinterpret_cast<const float4*>(x + (size_t)t * D_);
  double acc[E_];
  #pragma unroll
  for (int e = 0; e < E_; ++e) acc[e] = 0.0;
  #pragma unroll
  for (int j = 0; j < 4; ++j){
    float4 xv = xr[j*64 + lane];
    #pragma unroll
    for (int e = 0; e < E_; ++e){
      float4 wv = *reinterpret_cast<const float4*>(gw + (size_t)e*D_ + (j*64 + lane)*4);
      acc[e] += (double)xv.x*wv.x + (double)xv.y*wv.y + (double)xv.z*wv.z + (double)xv.w*wv.w;
    }
  }
  #pragma unroll
  for (int e = 0; e < E_; ++e){
    #pragma unroll
    for (int off = 32; off >= 1; off >>= 1)
      acc[e] += __shfl_xor(acc[e], off);
  }
  if (lane == 0){
    float l[E_];
    #pragma unroll
    for (int e = 0; e < E_; ++e) l[e] = (float)acc[e];
    int i0 = 0; float v0 = l[0];
    #pragma unroll
    for (int e = 1; e < E_; ++e) if (l[e] > v0){ v0 = l[e]; i0 = e; }
    int i1 = -1; float v1 = -1e30f;
    #pragma unroll
    for (int e = 0; e < E_; ++e) if (e != i0 && l[e] > v1){ v1 = l[e]; i1 = e; }
    float e1 = expf(v1 - v0);
    float s = 1.0f + e1;
    tidx[2*t] = i0; tidx[2*t+1] = i1;
    tw[2*t] = 1.0f / s; tw[2*t+1] = e1 / s;
  }
}

// ---------------- slot scan: deterministic histogram + prefix, single block ----------------
__global__ void slotscan_kernel(const int* __restrict__ tidx, int* __restrict__ counts,
                                int* __restrict__ tokSlot, int nAssign){
  __shared__ int cnt[256][E_];
  __shared__ int wtot[E_][4];
  __shared__ int ebase[E_];
  const int tid = threadIdx.x;
  const int lane = tid & 63, w = tid >> 6;
  const int per = (nAssign + 255) >> 8;
  const int base = tid * per;

  #pragma unroll
  for (int e = 0; e < E_; ++e) cnt[tid][e] = 0;
  for (int j = 0; j < per; ++j){
    int i = base + j;
    if (i < nAssign) cnt[tid][tidx[i]]++;
  }
  int excl[E_];
  #pragma unroll
  for (int e = 0; e < E_; ++e){
    int v = cnt[tid][e];
    int s = v;
    #pragma unroll
    for (int off = 1; off < 64; off <<= 1){
      int u = __shfl_up(s, off);
      if (lane >= off) s += u;
    }
    if (lane == 63) wtot[e][w] = s;
    excl[e] = s - v;
  }
  __syncthreads();
  if (tid == 0){
    int pre = 0;
    #pragma unroll
    for (int e = 0; e < E_; ++e){
      int tot = 0;
      #pragma unroll
      for (int ww = 0; ww < 4; ++ww){ int c = wtot[e][ww]; wtot[e][ww] = tot; tot += c; }
      counts[e] = tot;
      ebase[e] = pre;
      pre += (tot + (ALIGN_-1)) & ~(ALIGN_-1);
    }
  }
  __syncthreads();
  #pragma unroll
  for (int e = 0; e < E_; ++e)
    cnt[tid][e] = ebase[e] + wtot[e][w] + excl[e];
  for (int j = 0; j < per; ++j){
    int i = base + j;
    if (i < nAssign){
      int e = tidx[i];
      tokSlot[i] = cnt[tid][e]++;
    }
  }
}

// ---------------- gather: bf16 row copy to precomputed slots ----------------
__global__ void scatgath_kernel(const float* __restrict__ x,
                                const int* __restrict__ tokSlot,
                                __hip_bfloat16* __restrict__ Abuf){
  int t = blockIdx.x;
  int s0 = tokSlot[K_*t], s1 = tokSlot[K_*t + 1];
  const float4* src = reinterpret_cast<const float4*>(x + (size_t)t * D_) + threadIdx.x*2;
  float4 v0 = src[0], v1 = src[1];
  uint4 p;
  p.x = f2bf(v0.x) | (f2bf(v0.y) << 16);
  p.y = f2bf(v0.z) | (f2bf(v0.w) << 16);
  p.z = f2bf(v1.x) | (f2bf(v1.y) << 16);
  p.w = f2bf(v1.z) | (f2bf(v1.w) << 16);
  *(reinterpret_cast<uint4*>(reinterpret_cast<unsigned short*>(Abuf) + (size_t)s0*D_) + threadIdx.x) = p;
  *(reinterpret_cast<uint4*>(reinterpret_cast<unsigned short*>(Abuf) + (size_t)s1*D_) + threadIdx.x) = p;
}

// ---------------- weight fp32 -> bf16 ----------------
__global__ void cvtw_kernel(const float* __restrict__ src, __hip_bfloat16* __restrict__ dst, int n4){
  int stride = gridDim.x * blockDim.x;
  for (int i = blockIdx.x * blockDim.x + threadIdx.x; i < n4; i += stride){
    float4 v = reinterpret_cast<const float4*>(src)[i];
    uint2 p;
    p.x = f2bf(v.x) | (f2bf(v.y) << 16);
    p.y = f2bf(v.z) | (f2bf(v.w) << 16);
    reinterpret_cast<uint2*>(dst)[i] = p;
  }
}

// ---------------- combine: out[t] = sum_k w_k * (Y[slot_k] + b_proj[e_k]) ----------------
__global__ void combine_kernel(const unsigned short* __restrict__ Ybuf,
                               const int* __restrict__ tidx, const float* __restrict__ tw,
                               const int* __restrict__ tokSlot,
                               const float* __restrict__ bpj,
                               float* __restrict__ out){
  int t = blockIdx.x;
  int d = threadIdx.x * 4;
  int e0 = tidx[2*t], e1 = tidx[2*t+1];
  float w0 = tw[2*t], w1 = tw[2*t+1];
  int s0 = tokSlot[2*t], s1 = tokSlot[2*t+1];
  uint2 ya = *reinterpret_cast<const uint2*>(Ybuf + (size_t)s0*D_ + d);
  uint2 yb = *reinterpret_cast<const uint2*>(Ybuf + (size_t)s1*D_ + d);
  float4 b0 = *reinterpret_cast<const float4*>(bpj + (size_t)e0*D_ + d);
  float4 b1 = *reinterpret_cast<const float4*>(bpj + (size_t)e1*D_ + d);
  float4 r;
  r.x = w0*(bf2f(ya.x & 0xffffu) + b0.x) + w1*(bf2f(yb.x & 0xffffu) + b1.x);
  r.y = w0*(bf2f(ya.x >> 16)     + b0.y) + w1*(bf2f(yb.x >> 16)     + b1.y);
  r.z = w0*(bf2f(ya.y & 0xffffu) + b0.z) + w1*(bf2f(yb.y & 0xffffu) + b1.z);
  r.w = w0*(bf2f(ya.y >> 16)     + b0.w) + w1*(bf2f(yb.y >> 16)     + b1.w);
  *reinterpret_cast<float4*>(out + (size_t)t*D_ + d) = r;
}

// ---------------- 128x128 GEMM (m97 structure + XCD COLUMN-slab swizzle; 4 blocks/CU) ----------------
// PH1: H = gelu(A wfc^T + b) -> bf16 Hbuf[slot][F]
// PH2: Y = H wproj^T         -> bf16 Ybuf[slot][D]   (bias+route applied in combine)
// NOTE: __launch_bounds__ min-waves MUST stay 4: acc[4][4] needs 64 VGPRs;
// (256,5) capped VGPR at 48 -> accumulator spilled to scratch (R8: WRITE_SIZE 1.1 GB, 2x slower).
template<bool WB16, bool PH1>
__global__ __launch_bounds__(256, 4) void gemm_kernel(
    const __hip_bfloat16* __restrict__ Abuf,   // [rows][KA] bf16
    const void* __restrict__ W,                // [E][NT][KA] bf16 or fp32
    const float* __restrict__ bias,            // [E][NT] (PH1 only)
    const int* __restrict__ counts,
    unsigned short* __restrict__ Out16)
{
  constexpr int KA = PH1 ? D_ : F_;
  constexpr int NT = PH1 ? F_ : D_;
  constexpr int NK = KA / 64;
  constexpr int NX = NT / 128;

  __shared__ char sA[128*128];   // 16 KB
  __shared__ char sB[128*128];   // 16 KB

  int pre[E_]; int total = 0;
  #pragma unroll
  for (int i = 0; i < E_; ++i){ pre[i] = total; total += (counts[i] + (ALIGN_-1)) & ~(ALIGN_-1); }

  // bijective XCD COLUMN-slab swizzle: XCD c = bid&7 owns a contiguous wgid chunk;
  // row tiles fastest within chunk -> per-XCD concurrent B (weight) working set is
  // one ~256KB-1MB col-panel: L2-resident. A/H rows stream through the 256MB LLC.
  int q = gridDim.x >> 3;                        // gridDim.x % 8 == 0
  int wgid = (blockIdx.x & 7) * q + (blockIdx.x >> 3);
  constexpr int dummy = 0; (void)dummy;
  int NYt = gridDim.x / NX;                      // rowTiles
  int xt = wgid / NYt;                           // slow: column tile
  int yt = wgid - xt * NYt;                      // fast: row tile
  int rowBase = yt * 128;
  if (rowBase >= total) return;
  int e = 0;
  #pragma unroll
  for (int i = 1; i < E_; ++i) if (rowBase >= pre[i]) e = i;
  int nBase = xt * 128;

  const int tid = threadIdx.x;
  const int wid = tid >> 6, lane = tid & 63;
  const int lr = lane & 15, lg = lane >> 4;
  const int wr = wid >> 1, wc = wid & 1;

  const unsigned short* Wb = (const unsigned short*)W;
  const float* Wf = (const float*)W;
  const size_t Wrow0 = (size_t)e * NT + nBase;

  f32x4 acc[4][4];
  #pragma unroll
  for (int m = 0; m < 4; ++m)
    #pragma unroll
    for (int n = 0; n < 4; ++n) acc[m][n] = (f32x4){0.f,0.f,0.f,0.f};

  for (int kt = 0; kt < NK; ++kt){
    int k0 = kt * 64;
    // ---- stage A tile via global_load_lds (linear dest, inverse-swizzled source) ----
    #pragma unroll
    for (int i = 0; i < 4; ++i){
      int flat = i*4096 + wid*1024 + lane*16;
      int row  = flat >> 7;
      int colb = flat & 127;
      int scol = colb ^ ((row & 7) << 4);
      const char* src = (const char*)(Abuf + (size_t)(rowBase + row) * KA + k0) + scol;
      gload16(src, sA + i*4096 + wid*1024);
    }
    // ---- stage B tile ----
    if constexpr (WB16){
      #pragma unroll
      for (int i = 0; i < 4; ++i){
        int flat = i*4096 + wid*1024 + lane*16;
        int row  = flat >> 7;
        int colb = flat & 127;
        int scol = colb ^ ((row & 7) << 4);
        const char* src = (const char*)(Wb + (Wrow0 + row) * KA + k0) + scol;
        gload16(src, sB + i*4096 + wid*1024);
      }
    } else {
      // reg-stage fp32 -> bf16, write-side swizzle
      #pragma unroll
      for (int i = 0; i < 8; ++i){
        int f4  = i*256 + tid;
        int row = f4 >> 4;
        int c4  = f4 & 15;
        float4 v = *reinterpret_cast<const float4*>(Wf + (Wrow0 + row) * KA + k0 + c4*4);
        uint2 p;
        p.x = f2bf(v.x) | (f2bf(v.y) << 16);
        p.y = f2bf(v.z) | (f2bf(v.w) << 16);
        int byte = row*128 + c4*8;
        *reinterpret_cast<uint2*>(sB + (byte ^ ((row & 7) << 4))) = p;
      }
    }
    __syncthreads();
    // ---- compute (swapped operands: each thread holds 4 contiguous output cols) ----
    #pragma unroll
    for (int ks = 0; ks < 2; ++ks){
      short8 a[4], b[4];
      #pragma unroll
      for (int m = 0; m < 4; ++m){
        int row = wr*64 + m*16 + lr;
        a[m] = *reinterpret_cast<const short8*>(sA + row*128 + ((ks*64 + lg*16) ^ ((row & 7) << 4)));
      }
      #pragma unroll
      for (int n = 0; n < 4; ++n){
        int row = wc*64 + n*16 + lr;
        b[n] = *reinterpret_cast<const short8*>(sB + row*128 + ((ks*64 + lg*16) ^ ((row & 7) << 4)));
      }
      #pragma unroll
      for (int m = 0; m < 4; ++m)
        #pragma unroll
        for (int n = 0; n < 4; ++n)
          acc[m][n] = __builtin_amdgcn_mfma_f32_16x16x32_bf16(b[n], a[m], acc[m][n], 0, 0, 0);
    }
    __syncthreads();
  }

  // epilogue: rows rowBase+wr*64+m*16+lr ; cols nBase+wc*64+n*16+lg*4+{0..3}
  int colBase = nBase + wc*64;
  if constexpr (PH1){
    #pragma unroll
    for (int n = 0; n < 4; ++n){
      int gc = colBase + n*16 + lg*4;
      float4 b4 = *reinterpret_cast<const float4*>(bias + (size_t)e*F_ + gc);
      #pragma unroll
      for (int m = 0; m < 4; ++m){
        int gr = rowBase + wr*64 + m*16 + lr;
        uint2 p;
        p.x = f2bf(gelu_f(acc[m][n][0] + b4.x)) | (f2bf(gelu_f(acc[m][n][1] + b4.y)) << 16);
        p.y = f2bf(gelu_f(acc[m][n][2] + b4.z)) | (f2bf(gelu_f(acc[m][n][3] + b4.w)) << 16);
        *reinterpret_cast<uint2*>(Out16 + (size_t)gr * F_ + gc) = p;
      }
    }
  } else {
    #pragma unroll
    for (int n = 0; n < 4; ++n){
      int gc = colBase + n*16 + lg*4;
      #pragma unroll
      for (int m = 0; m < 4; ++m){
        int gr = rowBase + wr*64 + m*16 + lr;
        uint2 p;
        p.x = f2bf(acc[m][n][0]) | (f2bf(acc[m][n][1]) << 16);
        p.y = f2bf(acc[m][n][2]) | (f2bf(acc[m][n][3]) << 16);
        *reinterpret_cast<uint2*>(Out16 + (size_t)gr * D_ + gc) = p;
      }
    }
  }
}

extern "C" void kernel_launch(void* const* d_in, const int* in_sizes, int n_in,
                              void* d_out, int out_size, void* d_ws, size_t ws_size,
                              hipStream_t stream){
  const float* x   = (const float*)d_in[0];
  const float* gw  = (const float*)d_in[1];
  const float* wfc = (const float*)d_in[2];
  const float* bfc = (const float*)d_in[3];
  const float* wpj = (const float*)d_in[4];
  const float* bpj = (const float*)d_in[5];
  float* out = (float*)d_out;

  int T = in_sizes[0] / D_;               // 8192
  int nAssign = T * K_;
  int nSlotsMax = nAssign + E_ * ALIGN_;  // 17408
  int rowTiles = nSlotsMax / 128;         // 136

  char* ws = (char*)d_ws;
  size_t o = 0;
  int*   tidx    = (int*)(ws + o); o += (size_t)nAssign * 4;
  float* tw      = (float*)(ws + o); o += (size_t)nAssign * 4;
  int*   counts  = (int*)(ws + o); o += 256;
  int*   tokSlot = (int*)(ws + o); o += (size_t)nAssign * 4;
  o = (o + 255) & ~(size_t)255;

  size_t abytes = (size_t)nSlotsMax * D_ * 2;   // Abuf; reused as Ybuf after GEMM1
  size_t hbytes = (size_t)nSlotsMax * F_ * 2;
  size_t wbytes = (size_t)E_ * F_ * D_ * 2;

  __hip_bfloat16* Abuf = (__hip_bfloat16*)(ws + o); o += abytes;
  __hip_bfloat16* Hbuf = (__hip_bfloat16*)(ws + o); o += hbytes;
  size_t o_w = o;
  __hip_bfloat16* wA = (__hip_bfloat16*)(ws + o_w);
  __hip_bfloat16* wB = (__hip_bfloat16*)(ws + o_w + wbytes);

  bool newPath = (ws_size >= o_w + 2*wbytes);   // both weights upfront
  bool midPath = (ws_size >= o_w + wbytes);     // one buffer, serial reuse

  int n4 = E_ * F_ * D_ / 4;
  int nwg1 = (F_/128) * rowTiles;   // 4352, %8==0
  int nwg2 = (D_/128) * rowTiles;   // 1088, %8==0
  unsigned short* Ybuf = (unsigned short*)Abuf;

  gate_kernel<<<(T + 3)/4, 256, 0, stream>>>(x, gw, tidx, tw, T);
  slotscan_kernel<<<1, 256, 0, stream>>>(tidx, counts, tokSlot, nAssign);
  scatgath_kernel<<<T, 128, 0, stream>>>(x, tokSlot, Abuf);

  if (newPath){
    cvtw_kernel<<<2048, 256, 0, stream>>>(wfc, wA, n4);
    cvtw_kernel<<<2048, 256, 0, stream>>>(wpj, wB, n4);
    gemm_kernel<true, true><<<nwg1, 256, 0, stream>>>(
        Abuf, (const void*)wA, bfc, counts, (unsigned short*)Hbuf);
    gemm_kernel<true, false><<<nwg2, 256, 0, stream>>>(
        Hbuf, (const void*)wB, bpj, counts, Ybuf);
  } else if (midPath){
    cvtw_kernel<<<2048, 256, 0, stream>>>(wfc, wA, n4);
    gemm_kernel<true, true><<<nwg1, 256, 0, stream>>>(
        Abuf, (const void*)wA, bfc, counts, (unsigned short*)Hbuf);
    cvtw_kernel<<<2048, 256, 0, stream>>>(wpj, wA, n4);
    gemm_kernel<true, false><<<nwg2, 256, 0, stream>>>(
        Hbuf, (const void*)wA, bpj, counts, Ybuf);
  } else {
    gemm_kernel<false, true><<<nwg1, 256, 0, stream>>>(
        Abuf, (const void*)wfc, bfc, counts, (unsigned short*)Hbuf);
    gemm_kernel<false, false><<<nwg2, 256, 0, stream>>>(
        Hbuf, (const void*)wpj, bpj, counts, Ybuf);
  }
  combine_kernel<<<T, 256, 0, stream>>>(Ybuf, tidx, tw, tokSlot, bpj, out);
}

// Round 11
// 526.653 us; speedup vs baseline: 1.0821x; 1.0821x over previous
//
#include <hip/hip_runtime.h>
#include <hip/hip_bf16.h>

#define E_ 8
#define D_ 1024
#define F_ 4096
#define K_ 2
#define ALIGN_ 128

typedef __attribute__((ext_vector_type(8))) short short8;
typedef __attribute__((ext_vector_type(4))) float f32x4;

__device__ __forceinline__ unsigned f2bf(float f){
  union { __hip_bfloat16 h; unsigned short u; } c;
  c.h = __float2bfloat16(f);
  return (unsigned)c.u;
}

__device__ __forceinline__ float bf2f(unsigned u){
  union { float f; unsigned u; } c;
  c.u = u << 16;
  return c.f;
}

__device__ __forceinline__ float gelu_f(float v){
  const float c0 = 0.7978845608028654f;   // sqrt(2/pi)
  float z = c0 * (v + 0.044715f * v * v * v);
  float e = __expf(2.0f * z);
  float t = 1.0f - 2.0f / (1.0f + e);     // tanh(z), stable for |z| large
  return 0.5f * v * (1.0f + t);
}

__device__ __forceinline__ void gload16(const void* gsrc, void* ldst){
  __builtin_amdgcn_global_load_lds(
      (const __attribute__((address_space(1))) unsigned int*)gsrc,
      (__attribute__((address_space(3))) unsigned int*)ldst, 16, 0, 0);
}

// ---------------- gating: top-2 + softmax, no atomics, float4 loads ----------------
__global__ void gate_kernel(const float* __restrict__ x, const float* __restrict__ gw,
                            int* __restrict__ tidx, float* __restrict__ tw, int T){
  int wid = threadIdx.x >> 6, lane = threadIdx.x & 63;
  int t = blockIdx.x * 4 + wid;
  if (t >= T) return;
  const float4* xr = reinterpret_cast<const float4*>(x + (size_t)t * D_);
  double acc[E_];
  #pragma unroll
  for (int e = 0; e < E_; ++e) acc[e] = 0.0;
  #pragma unroll
  for (int j = 0; j < 4; ++j){
    float4 xv = xr[j*64 + lane];
    #pragma unroll
    for (int e = 0; e < E_; ++e){
      float4 wv = *reinterpret_cast<const float4*>(gw + (size_t)e*D_ + (j*64 + lane)*4);
      acc[e] += (double)xv.x*wv.x + (double)xv.y*wv.y + (double)xv.z*wv.z + (double)xv.w*wv.w;
    }
  }
  #pragma unroll
  for (int e = 0; e < E_; ++e){
    #pragma unroll
    for (int off = 32; off >= 1; off >>= 1)
      acc[e] += __shfl_xor(acc[e], off);
  }
  if (lane == 0){
    float l[E_];
    #pragma unroll
    for (int e = 0; e < E_; ++e) l[e] = (float)acc[e];
    int i0 = 0; float v0 = l[0];
    #pragma unroll
    for (int e = 1; e < E_; ++e) if (l[e] > v0){ v0 = l[e]; i0 = e; }
    int i1 = -1; float v1 = -1e30f;
    #pragma unroll
    for (int e = 0; e < E_; ++e) if (e != i0 && l[e] > v1){ v1 = l[e]; i1 = e; }
    float e1 = expf(v1 - v0);
    float s = 1.0f + e1;
    tidx[2*t] = i0; tidx[2*t+1] = i1;
    tw[2*t] = 1.0f / s; tw[2*t+1] = e1 / s;
  }
}

// ---------------- slot scan: deterministic histogram + prefix, single block ----------------
__global__ void slotscan_kernel(const int* __restrict__ tidx, int* __restrict__ counts,
                                int* __restrict__ tokSlot, int nAssign){
  __shared__ int cnt[256][E_];
  __shared__ int wtot[E_][4];
  __shared__ int ebase[E_];
  const int tid = threadIdx.x;
  const int lane = tid & 63, w = tid >> 6;
  const int per = (nAssign + 255) >> 8;
  const int base = tid * per;

  #pragma unroll
  for (int e = 0; e < E_; ++e) cnt[tid][e] = 0;
  for (int j = 0; j < per; ++j){
    int i = base + j;
    if (i < nAssign) cnt[tid][tidx[i]]++;
  }
  int excl[E_];
  #pragma unroll
  for (int e = 0; e < E_; ++e){
    int v = cnt[tid][e];
    int s = v;
    #pragma unroll
    for (int off = 1; off < 64; off <<= 1){
      int u = __shfl_up(s, off);
      if (lane >= off) s += u;
    }
    if (lane == 63) wtot[e][w] = s;
    excl[e] = s - v;
  }
  __syncthreads();
  if (tid == 0){
    int pre = 0;
    #pragma unroll
    for (int e = 0; e < E_; ++e){
      int tot = 0;
      #pragma unroll
      for (int ww = 0; ww < 4; ++ww){ int c = wtot[e][ww]; wtot[e][ww] = tot; tot += c; }
      counts[e] = tot;
      ebase[e] = pre;
      pre += (tot + (ALIGN_-1)) & ~(ALIGN_-1);
    }
  }
  __syncthreads();
  #pragma unroll
  for (int e = 0; e < E_; ++e)
    cnt[tid][e] = ebase[e] + wtot[e][w] + excl[e];
  for (int j = 0; j < per; ++j){
    int i = base + j;
    if (i < nAssign){
      int e = tidx[i];
      tokSlot[i] = cnt[tid][e]++;
    }
  }
}

// ---------------- gather: bf16 row copy to precomputed slots ----------------
__global__ void scatgath_kernel(const float* __restrict__ x,
                                const int* __restrict__ tokSlot,
                                __hip_bfloat16* __restrict__ Abuf){
  int t = blockIdx.x;
  int s0 = tokSlot[K_*t], s1 = tokSlot[K_*t + 1];
  const float4* src = reinterpret_cast<const float4*>(x + (size_t)t * D_) + threadIdx.x*2;
  float4 v0 = src[0], v1 = src[1];
  uint4 p;
  p.x = f2bf(v0.x) | (f2bf(v0.y) << 16);
  p.y = f2bf(v0.z) | (f2bf(v0.w) << 16);
  p.z = f2bf(v1.x) | (f2bf(v1.y) << 16);
  p.w = f2bf(v1.z) | (f2bf(v1.w) << 16);
  *(reinterpret_cast<uint4*>(reinterpret_cast<unsigned short*>(Abuf) + (size_t)s0*D_) + threadIdx.x) = p;
  *(reinterpret_cast<uint4*>(reinterpret_cast<unsigned short*>(Abuf) + (size_t)s1*D_) + threadIdx.x) = p;
}

// ---------------- weight fp32 -> bf16 ----------------
__global__ void cvtw_kernel(const float* __restrict__ src, __hip_bfloat16* __restrict__ dst, int n4){
  int stride = gridDim.x * blockDim.x;
  for (int i = blockIdx.x * blockDim.x + threadIdx.x; i < n4; i += stride){
    float4 v = reinterpret_cast<const float4*>(src)[i];
    uint2 p;
    p.x = f2bf(v.x) | (f2bf(v.y) << 16);
    p.y = f2bf(v.z) | (f2bf(v.w) << 16);
    reinterpret_cast<uint2*>(dst)[i] = p;
  }
}

// ---------------- combine: out[t] = sum_k w_k * (Y[slot_k] + b_proj[e_k]) ----------------
__global__ void combine_kernel(const unsigned short* __restrict__ Ybuf,
                               const int* __restrict__ tidx, const float* __restrict__ tw,
                               const int* __restrict__ tokSlot,
                               const float* __restrict__ bpj,
                               float* __restrict__ out){
  int t = blockIdx.x;
  int d = threadIdx.x * 4;
  int e0 = tidx[2*t], e1 = tidx[2*t+1];
  float w0 = tw[2*t], w1 = tw[2*t+1];
  int s0 = tokSlot[2*t], s1 = tokSlot[2*t+1];
  uint2 ya = *reinterpret_cast<const uint2*>(Ybuf + (size_t)s0*D_ + d);
  uint2 yb = *reinterpret_cast<const uint2*>(Ybuf + (size_t)s1*D_ + d);
  float4 b0 = *reinterpret_cast<const float4*>(bpj + (size_t)e0*D_ + d);
  float4 b1 = *reinterpret_cast<const float4*>(bpj + (size_t)e1*D_ + d);
  float4 r;
  r.x = w0*(bf2f(ya.x & 0xffffu) + b0.x) + w1*(bf2f(yb.x & 0xffffu) + b1.x);
  r.y = w0*(bf2f(ya.x >> 16)     + b0.y) + w1*(bf2f(yb.x >> 16)     + b1.y);
  r.z = w0*(bf2f(ya.y & 0xffffu) + b0.z) + w1*(bf2f(yb.y & 0xffffu) + b1.z);
  r.w = w0*(bf2f(ya.y >> 16)     + b0.w) + w1*(bf2f(yb.y >> 16)     + b1.w);
  *reinterpret_cast<float4*>(out + (size_t)t*D_ + d) = r;
}

// ---------------- 128x128 GEMM (m97 structure + XCD ROW-chunk swizzle; 4 blocks/CU) ----------------
// PH1: H = gelu(A wfc^T + b) -> bf16 Hbuf[slot][F]
// PH2: Y = H wproj^T         -> bf16 Ybuf[slot][D]   (bias+route applied in combine)
// NOTE: __launch_bounds__ min-waves MUST stay 4: acc[4][4] needs 64 VGPRs;
// (256,5) capped VGPR at 48 -> accumulator spilled to scratch (R8: WRITE_SIZE 1.1 GB, 2x slower).
// NOTE: grid mapping MUST be row-chunk (columns fastest within an XCD chunk): the XCD's
// concurrent A working set stays ~1 MB (L2-resident). Column-slab ordering (R10) re-streamed
// A per column tile: FETCH 448->581 MB, dur 196->220 us. Keep yt fast = columns fastest.
template<bool WB16, bool PH1>
__global__ __launch_bounds__(256, 4) void gemm_kernel(
    const __hip_bfloat16* __restrict__ Abuf,   // [rows][KA] bf16
    const void* __restrict__ W,                // [E][NT][KA] bf16 or fp32
    const float* __restrict__ bias,            // [E][NT] (PH1 only)
    const int* __restrict__ counts,
    unsigned short* __restrict__ Out16)
{
  constexpr int KA = PH1 ? D_ : F_;
  constexpr int NT = PH1 ? F_ : D_;
  constexpr int NK = KA / 64;
  constexpr int NX = NT / 128;

  __shared__ char sA[128*128];   // 16 KB
  __shared__ char sB[128*128];   // 16 KB

  int pre[E_]; int total = 0;
  #pragma unroll
  for (int i = 0; i < E_; ++i){ pre[i] = total; total += (counts[i] + (ALIGN_-1)) & ~(ALIGN_-1); }

  // bijective XCD row-chunk swizzle: XCD c = bid&7 owns a contiguous wgid chunk;
  // columns fastest within chunk -> A-slab L2-resident, weights served by LLC
  int q = gridDim.x >> 3;                        // gridDim.x % 8 == 0
  int wgid = (blockIdx.x & 7) * q + (blockIdx.x >> 3);
  int yt = wgid / NX, xt = wgid - yt*NX;         // xt (columns) fastest
  int rowBase = yt * 128;
  if (rowBase >= total) return;
  int e = 0;
  #pragma unroll
  for (int i = 1; i < E_; ++i) if (rowBase >= pre[i]) e = i;
  int nBase = xt * 128;

  const int tid = threadIdx.x;
  const int wid = tid >> 6, lane = tid & 63;
  const int lr = lane & 15, lg = lane >> 4;
  const int wr = wid >> 1, wc = wid & 1;

  const unsigned short* Wb = (const unsigned short*)W;
  const float* Wf = (const float*)W;
  const size_t Wrow0 = (size_t)e * NT + nBase;

  f32x4 acc[4][4];
  #pragma unroll
  for (int m = 0; m < 4; ++m)
    #pragma unroll
    for (int n = 0; n < 4; ++n) acc[m][n] = (f32x4){0.f,0.f,0.f,0.f};

  for (int kt = 0; kt < NK; ++kt){
    int k0 = kt * 64;
    // ---- stage A tile via global_load_lds (linear dest, inverse-swizzled source) ----
    #pragma unroll
    for (int i = 0; i < 4; ++i){
      int flat = i*4096 + wid*1024 + lane*16;
      int row  = flat >> 7;
      int colb = flat & 127;
      int scol = colb ^ ((row & 7) << 4);
      const char* src = (const char*)(Abuf + (size_t)(rowBase + row) * KA + k0) + scol;
      gload16(src, sA + i*4096 + wid*1024);
    }
    // ---- stage B tile ----
    if constexpr (WB16){
      #pragma unroll
      for (int i = 0; i < 4; ++i){
        int flat = i*4096 + wid*1024 + lane*16;
        int row  = flat >> 7;
        int colb = flat & 127;
        int scol = colb ^ ((row & 7) << 4);
        const char* src = (const char*)(Wb + (Wrow0 + row) * KA + k0) + scol;
        gload16(src, sB + i*4096 + wid*1024);
      }
    } else {
      // reg-stage fp32 -> bf16, write-side swizzle
      #pragma unroll
      for (int i = 0; i < 8; ++i){
        int f4  = i*256 + tid;
        int row = f4 >> 4;
        int c4  = f4 & 15;
        float4 v = *reinterpret_cast<const float4*>(Wf + (Wrow0 + row) * KA + k0 + c4*4);
        uint2 p;
        p.x = f2bf(v.x) | (f2bf(v.y) << 16);
        p.y = f2bf(v.z) | (f2bf(v.w) << 16);
        int byte = row*128 + c4*8;
        *reinterpret_cast<uint2*>(sB + (byte ^ ((row & 7) << 4))) = p;
      }
    }
    __syncthreads();
    // ---- compute (swapped operands: each thread holds 4 contiguous output cols) ----
    #pragma unroll
    for (int ks = 0; ks < 2; ++ks){
      short8 a[4], b[4];
      #pragma unroll
      for (int m = 0; m < 4; ++m){
        int row = wr*64 + m*16 + lr;
        a[m] = *reinterpret_cast<const short8*>(sA + row*128 + ((ks*64 + lg*16) ^ ((row & 7) << 4)));
      }
      #pragma unroll
      for (int n = 0; n < 4; ++n){
        int row = wc*64 + n*16 + lr;
        b[n] = *reinterpret_cast<const short8*>(sB + row*128 + ((ks*64 + lg*16) ^ ((row & 7) << 4)));
      }
      #pragma unroll
      for (int m = 0; m < 4; ++m)
        #pragma unroll
        for (int n = 0; n < 4; ++n)
          acc[m][n] = __builtin_amdgcn_mfma_f32_16x16x32_bf16(b[n], a[m], acc[m][n], 0, 0, 0);
    }
    __syncthreads();
  }

  // epilogue: rows rowBase+wr*64+m*16+lr ; cols nBase+wc*64+n*16+lg*4+{0..3}
  int colBase = nBase + wc*64;
  if constexpr (PH1){
    #pragma unroll
    for (int n = 0; n < 4; ++n){
      int gc = colBase + n*16 + lg*4;
      float4 b4 = *reinterpret_cast<const float4*>(bias + (size_t)e*F_ + gc);
      #pragma unroll
      for (int m = 0; m < 4; ++m){
        int gr = rowBase + wr*64 + m*16 + lr;
        uint2 p;
        p.x = f2bf(gelu_f(acc[m][n][0] + b4.x)) | (f2bf(gelu_f(acc[m][n][1] + b4.y)) << 16);
        p.y = f2bf(gelu_f(acc[m][n][2] + b4.z)) | (f2bf(gelu_f(acc[m][n][3] + b4.w)) << 16);
        *reinterpret_cast<uint2*>(Out16 + (size_t)gr * F_ + gc) = p;
      }
    }
  } else {
    #pragma unroll
    for (int n = 0; n < 4; ++n){
      int gc = colBase + n*16 + lg*4;
      #pragma unroll
      for (int m = 0; m < 4; ++m){
        int gr = rowBase + wr*64 + m*16 + lr;
        uint2 p;
        p.x = f2bf(acc[m][n][0]) | (f2bf(acc[m][n][1]) << 16);
        p.y = f2bf(acc[m][n][2]) | (f2bf(acc[m][n][3]) << 16);
        *reinterpret_cast<uint2*>(Out16 + (size_t)gr * D_ + gc) = p;
      }
    }
  }
}

extern "C" void kernel_launch(void* const* d_in, const int* in_sizes, int n_in,
                              void* d_out, int out_size, void* d_ws, size_t ws_size,
                              hipStream_t stream){
  const float* x   = (const float*)d_in[0];
  const float* gw  = (const float*)d_in[1];
  const float* wfc = (const float*)d_in[2];
  const float* bfc = (const float*)d_in[3];
  const float* wpj = (const float*)d_in[4];
  const float* bpj = (const float*)d_in[5];
  float* out = (float*)d_out;

  int T = in_sizes[0] / D_;               // 8192
  int nAssign = T * K_;
  int nSlotsMax = nAssign + E_ * ALIGN_;  // 17408
  int rowTiles = nSlotsMax / 128;         // 136

  char* ws = (char*)d_ws;
  size_t o = 0;
  int*   tidx    = (int*)(ws + o); o += (size_t)nAssign * 4;
  float* tw      = (float*)(ws + o); o += (size_t)nAssign * 4;
  int*   counts  = (int*)(ws + o); o += 256;
  int*   tokSlot = (int*)(ws + o); o += (size_t)nAssign * 4;
  o = (o + 255) & ~(size_t)255;

  size_t abytes = (size_t)nSlotsMax * D_ * 2;   // Abuf; reused as Ybuf after GEMM1
  size_t hbytes = (size_t)nSlotsMax * F_ * 2;
  size_t wbytes = (size_t)E_ * F_ * D_ * 2;

  __hip_bfloat16* Abuf = (__hip_bfloat16*)(ws + o); o += abytes;
  __hip_bfloat16* Hbuf = (__hip_bfloat16*)(ws + o); o += hbytes;
  size_t o_w = o;
  __hip_bfloat16* wA = (__hip_bfloat16*)(ws + o_w);
  __hip_bfloat16* wB = (__hip_bfloat16*)(ws + o_w + wbytes);

  bool newPath = (ws_size >= o_w + 2*wbytes);   // both weights upfront
  bool midPath = (ws_size >= o_w + wbytes);     // one buffer, serial reuse

  int n4 = E_ * F_ * D_ / 4;
  int nwg1 = (F_/128) * rowTiles;   // 4352, %8==0
  int nwg2 = (D_/128) * rowTiles;   // 1088, %8==0
  unsigned short* Ybuf = (unsigned short*)Abuf;

  gate_kernel<<<(T + 3)/4, 256, 0, stream>>>(x, gw, tidx, tw, T);
  slotscan_kernel<<<1, 256, 0, stream>>>(tidx, counts, tokSlot, nAssign);
  scatgath_kernel<<<T, 128, 0, stream>>>(x, tokSlot, Abuf);

  if (newPath){
    cvtw_kernel<<<2048, 256, 0, stream>>>(wfc, wA, n4);
    cvtw_kernel<<<2048, 256, 0, stream>>>(wpj, wB, n4);
    gemm_kernel<true, true><<<nwg1, 256, 0, stream>>>(
        Abuf, (const void*)wA, bfc, counts, (unsigned short*)Hbuf);
    gemm_kernel<true, false><<<nwg2, 256, 0, stream>>>(
        Hbuf, (const void*)wB, bpj, counts, Ybuf);
  } else if (midPath){
    cvtw_kernel<<<2048, 256, 0, stream>>>(wfc, wA, n4);
    gemm_kernel<true, true><<<nwg1, 256, 0, stream>>>(
        Abuf, (const void*)wA, bfc, counts, (unsigned short*)Hbuf);
    cvtw_kernel<<<2048, 256, 0, stream>>>(wpj, wA, n4);
    gemm_kernel<true, false><<<nwg2, 256, 0, stream>>>(
        Hbuf, (const void*)wA, bpj, counts, Ybuf);
  } else {
    gemm_kernel<false, true><<<nwg1, 256, 0, stream>>>(
        Abuf, (const void*)wfc, bfc, counts, (unsigned short*)Hbuf);
    gemm_kernel<false, false><<<nwg2, 256, 0, stream>>>(
        Hbuf, (const void*)wpj, bpj, counts, Ybuf);
  }
  combine_kernel<<<T, 256, 0, stream>>>(Ybuf, tidx, tw, tokSlot, bpj, out);
}

// Round 12
// 524.635 us; speedup vs baseline: 1.0862x; 1.0038x over previous
//
#include <hip/hip_runtime.h>
#include <hip/hip_bf16.h>

#define E_ 8
#define D_ 1024
#define F_ 4096
#define K_ 2
#define ALIGN_ 128

typedef __attribute__((ext_vector_type(8))) short short8;
typedef __attribute__((ext_vector_type(4))) float f32x4;

__device__ __forceinline__ unsigned f2bf(float f){
  union { __hip_bfloat16 h; unsigned short u; } c;
  c.h = __float2bfloat16(f);
  return (unsigned)c.u;
}

__device__ __forceinline__ float bf2f(unsigned u){
  union { float f; unsigned u; } c;
  c.u = u << 16;
  return c.f;
}

__device__ __forceinline__ float gelu_f(float v){
  const float c0 = 0.7978845608028654f;   // sqrt(2/pi)
  float z = c0 * (v + 0.044715f * v * v * v);
  float e = __expf(2.0f * z);
  float t = 1.0f - 2.0f / (1.0f + e);     // tanh(z), stable for |z| large
  return 0.5f * v * (1.0f + t);
}

__device__ __forceinline__ void gload16(const void* gsrc, void* ldst){
  __builtin_amdgcn_global_load_lds(
      (const __attribute__((address_space(1))) unsigned int*)gsrc,
      (__attribute__((address_space(3))) unsigned int*)ldst, 16, 0, 0);
}

// ---------------- gating: top-2 + softmax + token-ordered bf16 x copy ----------------
__global__ void gate_kernel(const float* __restrict__ x, const float* __restrict__ gw,
                            int* __restrict__ tidx, float* __restrict__ tw,
                            unsigned short* __restrict__ x16, int T){
  int wid = threadIdx.x >> 6, lane = threadIdx.x & 63;
  int t = blockIdx.x * 4 + wid;
  if (t >= T) return;
  const float4* xr = reinterpret_cast<const float4*>(x + (size_t)t * D_);
  uint2* x16r = reinterpret_cast<uint2*>(x16 + (size_t)t * D_);
  double acc[E_];
  #pragma unroll
  for (int e = 0; e < E_; ++e) acc[e] = 0.0;
  #pragma unroll
  for (int j = 0; j < 4; ++j){
    float4 xv = xr[j*64 + lane];
    uint2 p;
    p.x = f2bf(xv.x) | (f2bf(xv.y) << 16);
    p.y = f2bf(xv.z) | (f2bf(xv.w) << 16);
    x16r[j*64 + lane] = p;                 // bf16 copy for scatgath (saves 100 MB re-read)
    #pragma unroll
    for (int e = 0; e < E_; ++e){
      float4 wv = *reinterpret_cast<const float4*>(gw + (size_t)e*D_ + (j*64 + lane)*4);
      acc[e] += (double)xv.x*wv.x + (double)xv.y*wv.y + (double)xv.z*wv.z + (double)xv.w*wv.w;
    }
  }
  #pragma unroll
  for (int e = 0; e < E_; ++e){
    #pragma unroll
    for (int off = 32; off >= 1; off >>= 1)
      acc[e] += __shfl_xor(acc[e], off);
  }
  if (lane == 0){
    float l[E_];
    #pragma unroll
    for (int e = 0; e < E_; ++e) l[e] = (float)acc[e];
    int i0 = 0; float v0 = l[0];
    #pragma unroll
    for (int e = 1; e < E_; ++e) if (l[e] > v0){ v0 = l[e]; i0 = e; }
    int i1 = -1; float v1 = -1e30f;
    #pragma unroll
    for (int e = 0; e < E_; ++e) if (e != i0 && l[e] > v1){ v1 = l[e]; i1 = e; }
    float e1 = expf(v1 - v0);
    float s = 1.0f + e1;
    tidx[2*t] = i0; tidx[2*t+1] = i1;
    tw[2*t] = 1.0f / s; tw[2*t+1] = e1 / s;
  }
}

// ---------------- slot scan: deterministic histogram + prefix, single block ----------------
__global__ void slotscan_kernel(const int* __restrict__ tidx, int* __restrict__ counts,
                                int* __restrict__ tokSlot, int nAssign){
  __shared__ int cnt[256][E_];
  __shared__ int wtot[E_][4];
  __shared__ int ebase[E_];
  const int tid = threadIdx.x;
  const int lane = tid & 63, w = tid >> 6;
  const int per = (nAssign + 255) >> 8;
  const int base = tid * per;

  #pragma unroll
  for (int e = 0; e < E_; ++e) cnt[tid][e] = 0;
  for (int j = 0; j < per; ++j){
    int i = base + j;
    if (i < nAssign) cnt[tid][tidx[i]]++;
  }
  int excl[E_];
  #pragma unroll
  for (int e = 0; e < E_; ++e){
    int v = cnt[tid][e];
    int s = v;
    #pragma unroll
    for (int off = 1; off < 64; off <<= 1){
      int u = __shfl_up(s, off);
      if (lane >= off) s += u;
    }
    if (lane == 63) wtot[e][w] = s;
    excl[e] = s - v;
  }
  __syncthreads();
  if (tid == 0){
    int pre = 0;
    #pragma unroll
    for (int e = 0; e < E_; ++e){
      int tot = 0;
      #pragma unroll
      for (int ww = 0; ww < 4; ++ww){ int c = wtot[e][ww]; wtot[e][ww] = tot; tot += c; }
      counts[e] = tot;
      ebase[e] = pre;
      pre += (tot + (ALIGN_-1)) & ~(ALIGN_-1);
    }
  }
  __syncthreads();
  #pragma unroll
  for (int e = 0; e < E_; ++e)
    cnt[tid][e] = ebase[e] + wtot[e][w] + excl[e];
  for (int j = 0; j < per; ++j){
    int i = base + j;
    if (i < nAssign){
      int e = tidx[i];
      tokSlot[i] = cnt[tid][e]++;
    }
  }
}

// ---------------- gather: bf16 row copy (from x16) to precomputed slots ----------------
__global__ void scatgath_kernel(const unsigned short* __restrict__ x16,
                                const int* __restrict__ tokSlot,
                                __hip_bfloat16* __restrict__ Abuf){
  int t = blockIdx.x;
  int s0 = tokSlot[K_*t], s1 = tokSlot[K_*t + 1];
  uint4 p = *(reinterpret_cast<const uint4*>(x16 + (size_t)t * D_) + threadIdx.x);
  *(reinterpret_cast<uint4*>(reinterpret_cast<unsigned short*>(Abuf) + (size_t)s0*D_) + threadIdx.x) = p;
  *(reinterpret_cast<uint4*>(reinterpret_cast<unsigned short*>(Abuf) + (size_t)s1*D_) + threadIdx.x) = p;
}

// ---------------- weight fp32 -> bf16 ----------------
__global__ void cvtw_kernel(const float* __restrict__ src, __hip_bfloat16* __restrict__ dst, int n4){
  int stride = gridDim.x * blockDim.x;
  for (int i = blockIdx.x * blockDim.x + threadIdx.x; i < n4; i += stride){
    float4 v = reinterpret_cast<const float4*>(src)[i];
    uint2 p;
    p.x = f2bf(v.x) | (f2bf(v.y) << 16);
    p.y = f2bf(v.z) | (f2bf(v.w) << 16);
    reinterpret_cast<uint2*>(dst)[i] = p;
  }
}

// ---------------- combine: out[t] = sum_k w_k * (Y[slot_k] + b_proj[e_k]) ----------------
__global__ void combine_kernel(const unsigned short* __restrict__ Ybuf,
                               const int* __restrict__ tidx, const float* __restrict__ tw,
                               const int* __restrict__ tokSlot,
                               const float* __restrict__ bpj,
                               float* __restrict__ out){
  int t = blockIdx.x;
  int d = threadIdx.x * 4;
  int e0 = tidx[2*t], e1 = tidx[2*t+1];
  float w0 = tw[2*t], w1 = tw[2*t+1];
  int s0 = tokSlot[2*t], s1 = tokSlot[2*t+1];
  uint2 ya = *reinterpret_cast<const uint2*>(Ybuf + (size_t)s0*D_ + d);
  uint2 yb = *reinterpret_cast<const uint2*>(Ybuf + (size_t)s1*D_ + d);
  float4 b0 = *reinterpret_cast<const float4*>(bpj + (size_t)e0*D_ + d);
  float4 b1 = *reinterpret_cast<const float4*>(bpj + (size_t)e1*D_ + d);
  float4 r;
  r.x = w0*(bf2f(ya.x & 0xffffu) + b0.x) + w1*(bf2f(yb.x & 0xffffu) + b1.x);
  r.y = w0*(bf2f(ya.x >> 16)     + b0.y) + w1*(bf2f(yb.x >> 16)     + b1.y);
  r.z = w0*(bf2f(ya.y & 0xffffu) + b0.z) + w1*(bf2f(yb.y & 0xffffu) + b1.z);
  r.w = w0*(bf2f(ya.y >> 16)     + b0.w) + w1*(bf2f(yb.y >> 16)     + b1.w);
  *reinterpret_cast<float4*>(out + (size_t)t*D_ + d) = r;
}

// ---------------- 128x128 GEMM (m97 structure + XCD ROW-chunk swizzle; 4 blocks/CU) ----------------
// PH1: H = gelu(A wfc^T + b) -> bf16 Hbuf[slot][F]
// PH2: Y = H wproj^T         -> bf16 Ybuf[slot][D]   (bias+route applied in combine)
// NOTE: __launch_bounds__ min-waves MUST stay 4: acc[4][4] needs 64 VGPRs;
// (256,5) capped VGPR at 48 -> accumulator spilled to scratch (R8: WRITE_SIZE 1.1 GB, 2x slower).
// NOTE: grid mapping MUST be row-chunk (columns fastest within an XCD chunk): the XCD's
// concurrent A working set stays ~1 MB (L2-resident). Column-slab ordering (R10) re-streamed
// A per column tile: FETCH 448->581 MB, dur 196->220 us. Keep xt (columns) fastest.
template<bool WB16, bool PH1>
__global__ __launch_bounds__(256, 4) void gemm_kernel(
    const __hip_bfloat16* __restrict__ Abuf,   // [rows][KA] bf16
    const void* __restrict__ W,                // [E][NT][KA] bf16 or fp32
    const float* __restrict__ bias,            // [E][NT] (PH1 only)
    const int* __restrict__ counts,
    unsigned short* __restrict__ Out16)
{
  constexpr int KA = PH1 ? D_ : F_;
  constexpr int NT = PH1 ? F_ : D_;
  constexpr int NK = KA / 64;
  constexpr int NX = NT / 128;

  __shared__ char sA[128*128];   // 16 KB
  __shared__ char sB[128*128];   // 16 KB

  int pre[E_]; int total = 0;
  #pragma unroll
  for (int i = 0; i < E_; ++i){ pre[i] = total; total += (counts[i] + (ALIGN_-1)) & ~(ALIGN_-1); }

  // bijective XCD row-chunk swizzle: XCD c = bid&7 owns a contiguous wgid chunk;
  // columns fastest within chunk -> A-slab L2-resident, weights served by LLC
  int q = gridDim.x >> 3;                        // gridDim.x % 8 == 0
  int wgid = (blockIdx.x & 7) * q + (blockIdx.x >> 3);
  int yt = wgid / NX, xt = wgid - yt*NX;         // xt (columns) fastest
  int rowBase = yt * 128;
  if (rowBase >= total) return;
  int e = 0;
  #pragma unroll
  for (int i = 1; i < E_; ++i) if (rowBase >= pre[i]) e = i;
  int nBase = xt * 128;

  const int tid = threadIdx.x;
  const int wid = tid >> 6, lane = tid & 63;
  const int lr = lane & 15, lg = lane >> 4;
  const int wr = wid >> 1, wc = wid & 1;

  const unsigned short* Wb = (const unsigned short*)W;
  const float* Wf = (const float*)W;
  const size_t Wrow0 = (size_t)e * NT + nBase;

  f32x4 acc[4][4];
  #pragma unroll
  for (int m = 0; m < 4; ++m)
    #pragma unroll
    for (int n = 0; n < 4; ++n) acc[m][n] = (f32x4){0.f,0.f,0.f,0.f};

  for (int kt = 0; kt < NK; ++kt){
    int k0 = kt * 64;
    // ---- stage A tile via global_load_lds (linear dest, inverse-swizzled source) ----
    #pragma unroll
    for (int i = 0; i < 4; ++i){
      int flat = i*4096 + wid*1024 + lane*16;
      int row  = flat >> 7;
      int colb = flat & 127;
      int scol = colb ^ ((row & 7) << 4);
      const char* src = (const char*)(Abuf + (size_t)(rowBase + row) * KA + k0) + scol;
      gload16(src, sA + i*4096 + wid*1024);
    }
    // ---- stage B tile ----
    if constexpr (WB16){
      #pragma unroll
      for (int i = 0; i < 4; ++i){
        int flat = i*4096 + wid*1024 + lane*16;
        int row  = flat >> 7;
        int colb = flat & 127;
        int scol = colb ^ ((row & 7) << 4);
        const char* src = (const char*)(Wb + (Wrow0 + row) * KA + k0) + scol;
        gload16(src, sB + i*4096 + wid*1024);
      }
    } else {
      // reg-stage fp32 -> bf16, write-side swizzle
      #pragma unroll
      for (int i = 0; i < 8; ++i){
        int f4  = i*256 + tid;
        int row = f4 >> 4;
        int c4  = f4 & 15;
        float4 v = *reinterpret_cast<const float4*>(Wf + (Wrow0 + row) * KA + k0 + c4*4);
        uint2 p;
        p.x = f2bf(v.x) | (f2bf(v.y) << 16);
        p.y = f2bf(v.z) | (f2bf(v.w) << 16);
        int byte = row*128 + c4*8;
        *reinterpret_cast<uint2*>(sB + (byte ^ ((row & 7) << 4))) = p;
      }
    }
    __syncthreads();
    // ---- compute (swapped operands: each thread holds 4 contiguous output cols) ----
    #pragma unroll
    for (int ks = 0; ks < 2; ++ks){
      short8 a[4], b[4];
      #pragma unroll
      for (int m = 0; m < 4; ++m){
        int row = wr*64 + m*16 + lr;
        a[m] = *reinterpret_cast<const short8*>(sA + row*128 + ((ks*64 + lg*16) ^ ((row & 7) << 4)));
      }
      #pragma unroll
      for (int n = 0; n < 4; ++n){
        int row = wc*64 + n*16 + lr;
        b[n] = *reinterpret_cast<const short8*>(sB + row*128 + ((ks*64 + lg*16) ^ ((row & 7) << 4)));
      }
      #pragma unroll
      for (int m = 0; m < 4; ++m)
        #pragma unroll
        for (int n = 0; n < 4; ++n)
          acc[m][n] = __builtin_amdgcn_mfma_f32_16x16x32_bf16(b[n], a[m], acc[m][n], 0, 0, 0);
    }
    __syncthreads();
  }

  // epilogue: rows rowBase+wr*64+m*16+lr ; cols nBase+wc*64+n*16+lg*4+{0..3}
  int colBase = nBase + wc*64;
  if constexpr (PH1){
    #pragma unroll
    for (int n = 0; n < 4; ++n){
      int gc = colBase + n*16 + lg*4;
      float4 b4 = *reinterpret_cast<const float4*>(bias + (size_t)e*F_ + gc);
      #pragma unroll
      for (int m = 0; m < 4; ++m){
        int gr = rowBase + wr*64 + m*16 + lr;
        uint2 p;
        p.x = f2bf(gelu_f(acc[m][n][0] + b4.x)) | (f2bf(gelu_f(acc[m][n][1] + b4.y)) << 16);
        p.y = f2bf(gelu_f(acc[m][n][2] + b4.z)) | (f2bf(gelu_f(acc[m][n][3] + b4.w)) << 16);
        *reinterpret_cast<uint2*>(Out16 + (size_t)gr * F_ + gc) = p;
      }
    }
  } else {
    #pragma unroll
    for (int n = 0; n < 4; ++n){
      int gc = colBase + n*16 + lg*4;
      #pragma unroll
      for (int m = 0; m < 4; ++m){
        int gr = rowBase + wr*64 + m*16 + lr;
        uint2 p;
        p.x = f2bf(acc[m][n][0]) | (f2bf(acc[m][n][1]) << 16);
        p.y = f2bf(acc[m][n][2]) | (f2bf(acc[m][n][3]) << 16);
        *reinterpret_cast<uint2*>(Out16 + (size_t)gr * D_ + gc) = p;
      }
    }
  }
}

extern "C" void kernel_launch(void* const* d_in, const int* in_sizes, int n_in,
                              void* d_out, int out_size, void* d_ws, size_t ws_size,
                              hipStream_t stream){
  const float* x   = (const float*)d_in[0];
  const float* gw  = (const float*)d_in[1];
  const float* wfc = (const float*)d_in[2];
  const float* bfc = (const float*)d_in[3];
  const float* wpj = (const float*)d_in[4];
  const float* bpj = (const float*)d_in[5];
  float* out = (float*)d_out;

  int T = in_sizes[0] / D_;               // 8192
  int nAssign = T * K_;
  int nSlotsMax = nAssign + E_ * ALIGN_;  // 17408
  int rowTiles = nSlotsMax / 128;         // 136

  char* ws = (char*)d_ws;
  size_t o = 0;
  int*   tidx    = (int*)(ws + o); o += (size_t)nAssign * 4;
  float* tw      = (float*)(ws + o); o += (size_t)nAssign * 4;
  int*   counts  = (int*)(ws + o); o += 256;
  int*   tokSlot = (int*)(ws + o); o += (size_t)nAssign * 4;
  o = (o + 255) & ~(size_t)255;

  size_t abytes = (size_t)nSlotsMax * D_ * 2;   // Abuf; reused as Ybuf after GEMM1
  size_t hbytes = (size_t)nSlotsMax * F_ * 2;
  size_t wbytes = (size_t)E_ * F_ * D_ * 2;

  __hip_bfloat16* Abuf = (__hip_bfloat16*)(ws + o); o += abytes;
  __hip_bfloat16* Hbuf = (__hip_bfloat16*)(ws + o); o += hbytes;
  size_t o_w = o;
  __hip_bfloat16* wA = (__hip_bfloat16*)(ws + o_w);
  __hip_bfloat16* wB = (__hip_bfloat16*)(ws + o_w + wbytes);

  // x16: token-ordered bf16 copy of x, live only between gate and scatgath.
  // Aliases the FRONT of Hbuf (16 MB < 136 MB): GEMM1's Hbuf writes are stream-ordered
  // after scatgath's x16 reads, so no overlap hazard and no ws growth.
  unsigned short* x16 = (unsigned short*)Hbuf;

  bool newPath = (ws_size >= o_w + 2*wbytes);   // both weights upfront
  bool midPath = (ws_size >= o_w + wbytes);     // one buffer, serial reuse

  int n4 = E_ * F_ * D_ / 4;
  int nwg1 = (F_/128) * rowTiles;   // 4352, %8==0
  int nwg2 = (D_/128) * rowTiles;   // 1088, %8==0
  unsigned short* Ybuf = (unsigned short*)Abuf;

  gate_kernel<<<(T + 3)/4, 256, 0, stream>>>(x, gw, tidx, tw, x16, T);
  slotscan_kernel<<<1, 256, 0, stream>>>(tidx, counts, tokSlot, nAssign);
  scatgath_kernel<<<T, 128, 0, stream>>>(x16, tokSlot, Abuf);

  if (newPath){
    cvtw_kernel<<<2048, 256, 0, stream>>>(wfc, wA, n4);
    cvtw_kernel<<<2048, 256, 0, stream>>>(wpj, wB, n4);
    gemm_kernel<true, true><<<nwg1, 256, 0, stream>>>(
        Abuf, (const void*)wA, bfc, counts, (unsigned short*)Hbuf);
    gemm_kernel<true, false><<<nwg2, 256, 0, stream>>>(
        Hbuf, (const void*)wB, bpj, counts, Ybuf);
  } else if (midPath){
    cvtw_kernel<<<2048, 256, 0, stream>>>(wfc, wA, n4);
    gemm_kernel<true, true><<<nwg1, 256, 0, stream>>>(
        Abuf, (const void*)wA, bfc, counts, (unsigned short*)Hbuf);
    cvtw_kernel<<<2048, 256, 0, stream>>>(wpj, wA, n4);
    gemm_kernel<true, false><<<nwg2, 256, 0, stream>>>(
        Hbuf, (const void*)wA, bpj, counts, Ybuf);
  } else {
    gemm_kernel<false, true><<<nwg1, 256, 0, stream>>>(
        Abuf, (const void*)wfc, bfc, counts, (unsigned short*)Hbuf);
    gemm_kernel<false, false><<<nwg2, 256, 0, stream>>>(
        Hbuf, (const void*)wpj, bpj, counts, Ybuf);
  }
  combine_kernel<<<T, 256, 0, stream>>>(Ybuf, tidx, tw, tokSlot, bpj, out);
}

// Round 13
// 506.666 us; speedup vs baseline: 1.1247x; 1.0355x over previous
//
#include <hip/hip_runtime.h>
#include <hip/hip_bf16.h>

#define E_ 8
#define D_ 1024
#define F_ 4096
#define K_ 2
#define ALIGN_ 128

typedef __attribute__((ext_vector_type(8))) short short8;
typedef __attribute__((ext_vector_type(4))) float f32x4;

__device__ __forceinline__ unsigned f2bf(float f){
  union { __hip_bfloat16 h; unsigned short u; } c;
  c.h = __float2bfloat16(f);
  return (unsigned)c.u;
}

__device__ __forceinline__ float bf2f(unsigned u){
  union { float f; unsigned u; } c;
  c.u = u << 16;
  return c.f;
}

__device__ __forceinline__ float gelu_f(float v){
  const float c0 = 0.7978845608028654f;   // sqrt(2/pi)
  float z = c0 * (v + 0.044715f * v * v * v);
  float e = __expf(2.0f * z);
  float t = 1.0f - 2.0f / (1.0f + e);     // tanh(z), stable for |z| large
  return 0.5f * v * (1.0f + t);
}

__device__ __forceinline__ void gload16(const void* gsrc, void* ldst){
  __builtin_amdgcn_global_load_lds(
      (const __attribute__((address_space(1))) unsigned int*)gsrc,
      (__attribute__((address_space(3))) unsigned int*)ldst, 16, 0, 0);
}

// grid-stride fp32 -> bf16 conversion over n4 float4 groups (blockDim must be 256)
__device__ __forceinline__ void cvt_range(const float* __restrict__ src,
                                          __hip_bfloat16* __restrict__ dst,
                                          int n4, int cb, int nCvt){
  size_t stride = (size_t)nCvt * 256;
  for (size_t i = (size_t)cb*256 + threadIdx.x; i < (size_t)n4; i += stride){
    float4 v = reinterpret_cast<const float4*>(src)[i];
    uint2 p;
    p.x = f2bf(v.x) | (f2bf(v.y) << 16);
    p.y = f2bf(v.z) | (f2bf(v.w) << 16);
    reinterpret_cast<uint2*>(dst)[i] = p;
  }
}

// ---------------- gating: top-2 + softmax + bf16 x copy; tail blocks convert wfc ----------------
__global__ void gatecvt_kernel(const float* __restrict__ x, const float* __restrict__ gw,
                               int* __restrict__ tidx, float* __restrict__ tw,
                               unsigned short* __restrict__ x16, int T,
                               const float* __restrict__ csrc, __hip_bfloat16* __restrict__ cdst,
                               int n4, int gateBlocks){
  if ((int)blockIdx.x >= gateBlocks){
    cvt_range(csrc, cdst, n4, blockIdx.x - gateBlocks, gridDim.x - gateBlocks);
    return;
  }
  int wid = threadIdx.x >> 6, lane = threadIdx.x & 63;
  int t = blockIdx.x * 4 + wid;
  if (t >= T) return;
  const float4* xr = reinterpret_cast<const float4*>(x + (size_t)t * D_);
  uint2* x16r = reinterpret_cast<uint2*>(x16 + (size_t)t * D_);
  double acc[E_];
  #pragma unroll
  for (int e = 0; e < E_; ++e) acc[e] = 0.0;
  #pragma unroll
  for (int j = 0; j < 4; ++j){
    float4 xv = xr[j*64 + lane];
    uint2 p;
    p.x = f2bf(xv.x) | (f2bf(xv.y) << 16);
    p.y = f2bf(xv.z) | (f2bf(xv.w) << 16);
    x16r[j*64 + lane] = p;                 // bf16 copy for scatgath
    #pragma unroll
    for (int e = 0; e < E_; ++e){
      float4 wv = *reinterpret_cast<const float4*>(gw + (size_t)e*D_ + (j*64 + lane)*4);
      acc[e] += (double)xv.x*wv.x + (double)xv.y*wv.y + (double)xv.z*wv.z + (double)xv.w*wv.w;
    }
  }
  #pragma unroll
  for (int e = 0; e < E_; ++e){
    #pragma unroll
    for (int off = 32; off >= 1; off >>= 1)
      acc[e] += __shfl_xor(acc[e], off);
  }
  if (lane == 0){
    float l[E_];
    #pragma unroll
    for (int e = 0; e < E_; ++e) l[e] = (float)acc[e];
    int i0 = 0; float v0 = l[0];
    #pragma unroll
    for (int e = 1; e < E_; ++e) if (l[e] > v0){ v0 = l[e]; i0 = e; }
    int i1 = -1; float v1 = -1e30f;
    #pragma unroll
    for (int e = 0; e < E_; ++e) if (e != i0 && l[e] > v1){ v1 = l[e]; i1 = e; }
    float e1 = expf(v1 - v0);
    float s = 1.0f + e1;
    tidx[2*t] = i0; tidx[2*t+1] = i1;
    tw[2*t] = 1.0f / s; tw[2*t+1] = e1 / s;
  }
}

// ---------------- slot scan: deterministic histogram + prefix, single block ----------------
__global__ void slotscan_kernel(const int* __restrict__ tidx, int* __restrict__ counts,
                                int* __restrict__ tokSlot, int nAssign){
  __shared__ int cnt[256][E_];
  __shared__ int wtot[E_][4];
  __shared__ int ebase[E_];
  const int tid = threadIdx.x;
  const int lane = tid & 63, w = tid >> 6;
  const int per = (nAssign + 255) >> 8;
  const int base = tid * per;

  #pragma unroll
  for (int e = 0; e < E_; ++e) cnt[tid][e] = 0;
  for (int j = 0; j < per; ++j){
    int i = base + j;
    if (i < nAssign) cnt[tid][tidx[i]]++;
  }
  int excl[E_];
  #pragma unroll
  for (int e = 0; e < E_; ++e){
    int v = cnt[tid][e];
    int s = v;
    #pragma unroll
    for (int off = 1; off < 64; off <<= 1){
      int u = __shfl_up(s, off);
      if (lane >= off) s += u;
    }
    if (lane == 63) wtot[e][w] = s;
    excl[e] = s - v;
  }
  __syncthreads();
  if (tid == 0){
    int pre = 0;
    #pragma unroll
    for (int e = 0; e < E_; ++e){
      int tot = 0;
      #pragma unroll
      for (int ww = 0; ww < 4; ++ww){ int c = wtot[e][ww]; wtot[e][ww] = tot; tot += c; }
      counts[e] = tot;
      ebase[e] = pre;
      pre += (tot + (ALIGN_-1)) & ~(ALIGN_-1);
    }
  }
  __syncthreads();
  #pragma unroll
  for (int e = 0; e < E_; ++e)
    cnt[tid][e] = ebase[e] + wtot[e][w] + excl[e];
  for (int j = 0; j < per; ++j){
    int i = base + j;
    if (i < nAssign){
      int e = tidx[i];
      tokSlot[i] = cnt[tid][e]++;
    }
  }
}

// ---------------- gather: bf16 row copy (from x16) to precomputed slots ----------------
__global__ void scatgath_kernel(const unsigned short* __restrict__ x16,
                                const int* __restrict__ tokSlot,
                                __hip_bfloat16* __restrict__ Abuf){
  int t = blockIdx.x;
  int s0 = tokSlot[K_*t], s1 = tokSlot[K_*t + 1];
  uint4 p = *(reinterpret_cast<const uint4*>(x16 + (size_t)t * D_) + threadIdx.x);
  *(reinterpret_cast<uint4*>(reinterpret_cast<unsigned short*>(Abuf) + (size_t)s0*D_) + threadIdx.x) = p;
  *(reinterpret_cast<uint4*>(reinterpret_cast<unsigned short*>(Abuf) + (size_t)s1*D_) + threadIdx.x) = p;
}

// ---------------- standalone weight cvt (midPath / fallback) ----------------
__global__ void cvtw_kernel(const float* __restrict__ src, __hip_bfloat16* __restrict__ dst, int n4){
  cvt_range(src, dst, n4, blockIdx.x, gridDim.x);
}

// ---------------- combine: out[t] = sum_k w_k * (Y[slot_k] + b_proj[e_k]) ----------------
__global__ void combine_kernel(const unsigned short* __restrict__ Ybuf,
                               const int* __restrict__ tidx, const float* __restrict__ tw,
                               const int* __restrict__ tokSlot,
                               const float* __restrict__ bpj,
                               float* __restrict__ out){
  int t = blockIdx.x;
  int d = threadIdx.x * 4;
  int e0 = tidx[2*t], e1 = tidx[2*t+1];
  float w0 = tw[2*t], w1 = tw[2*t+1];
  int s0 = tokSlot[2*t], s1 = tokSlot[2*t+1];
  uint2 ya = *reinterpret_cast<const uint2*>(Ybuf + (size_t)s0*D_ + d);
  uint2 yb = *reinterpret_cast<const uint2*>(Ybuf + (size_t)s1*D_ + d);
  float4 b0 = *reinterpret_cast<const float4*>(bpj + (size_t)e0*D_ + d);
  float4 b1 = *reinterpret_cast<const float4*>(bpj + (size_t)e1*D_ + d);
  float4 r;
  r.x = w0*(bf2f(ya.x & 0xffffu) + b0.x) + w1*(bf2f(yb.x & 0xffffu) + b1.x);
  r.y = w0*(bf2f(ya.x >> 16)     + b0.y) + w1*(bf2f(yb.x >> 16)     + b1.y);
  r.z = w0*(bf2f(ya.y & 0xffffu) + b0.z) + w1*(bf2f(yb.y & 0xffffu) + b1.z);
  r.w = w0*(bf2f(ya.y >> 16)     + b0.w) + w1*(bf2f(yb.y >> 16)     + b1.w);
  *reinterpret_cast<float4*>(out + (size_t)t*D_ + d) = r;
}

// ---------------- 128x128 GEMM (m97 structure + XCD ROW-chunk swizzle; 4 blocks/CU) ----------------
// PH1: H = gelu(A wfc^T + b) -> bf16 Hbuf[slot][F]
// PH2: Y = H wproj^T         -> bf16 Ybuf[slot][D]   (bias+route applied in combine)
// Tail blocks (blockIdx >= nwgGemm) run a grid-stride fp32->bf16 weight conversion,
// co-scheduled in GEMM1's spare BW (GEMM1 runs at only ~54% of achievable HBM BW).
// NOTE: __launch_bounds__ min-waves MUST stay 4: acc[4][4] needs 64 VGPRs;
// (256,5) capped VGPR at 48 -> accumulator spilled to scratch (R8: WRITE_SIZE 1.1 GB, 2x slower).
// NOTE: grid mapping MUST be row-chunk (columns fastest within an XCD chunk): the XCD's
// concurrent A working set stays ~1 MB (L2-resident). Column-slab ordering (R10) re-streamed
// A per column tile: FETCH 448->581 MB, dur 196->220 us. Keep xt (columns) fastest.
template<bool WB16, bool PH1>
__global__ __launch_bounds__(256, 4) void gemm_kernel(
    const __hip_bfloat16* __restrict__ Abuf,   // [rows][KA] bf16
    const void* __restrict__ W,                // [E][NT][KA] bf16 or fp32
    const float* __restrict__ bias,            // [E][NT] (PH1 only)
    const int* __restrict__ counts,
    unsigned short* __restrict__ Out16,
    const float* __restrict__ csrc,            // optional tail-block cvt
    __hip_bfloat16* __restrict__ cdst,
    int n4, int nwgGemm)
{
  constexpr int KA = PH1 ? D_ : F_;
  constexpr int NT = PH1 ? F_ : D_;
  constexpr int NK = KA / 64;
  constexpr int NX = NT / 128;

  __shared__ char sA[128*128];   // 16 KB
  __shared__ char sB[128*128];   // 16 KB

  if ((int)blockIdx.x >= nwgGemm){
    cvt_range(csrc, cdst, n4, blockIdx.x - nwgGemm, gridDim.x - nwgGemm);
    return;
  }

  int pre[E_]; int total = 0;
  #pragma unroll
  for (int i = 0; i < E_; ++i){ pre[i] = total; total += (counts[i] + (ALIGN_-1)) & ~(ALIGN_-1); }

  // bijective XCD row-chunk swizzle over the GEMM sub-grid (nwgGemm % 8 == 0)
  int q = nwgGemm >> 3;
  int wgid = (blockIdx.x & 7) * q + (blockIdx.x >> 3);
  int yt = wgid / NX, xt = wgid - yt*NX;         // xt (columns) fastest
  int rowBase = yt * 128;
  if (rowBase >= total) return;
  int e = 0;
  #pragma unroll
  for (int i = 1; i < E_; ++i) if (rowBase >= pre[i]) e = i;
  int nBase = xt * 128;

  const int tid = threadIdx.x;
  const int wid = tid >> 6, lane = tid & 63;
  const int lr = lane & 15, lg = lane >> 4;
  const int wr = wid >> 1, wc = wid & 1;

  const unsigned short* Wb = (const unsigned short*)W;
  const float* Wf = (const float*)W;
  const size_t Wrow0 = (size_t)e * NT + nBase;

  f32x4 acc[4][4];
  #pragma unroll
  for (int m = 0; m < 4; ++m)
    #pragma unroll
    for (int n = 0; n < 4; ++n) acc[m][n] = (f32x4){0.f,0.f,0.f,0.f};

  for (int kt = 0; kt < NK; ++kt){
    int k0 = kt * 64;
    // ---- stage A tile via global_load_lds (linear dest, inverse-swizzled source) ----
    #pragma unroll
    for (int i = 0; i < 4; ++i){
      int flat = i*4096 + wid*1024 + lane*16;
      int row  = flat >> 7;
      int colb = flat & 127;
      int scol = colb ^ ((row & 7) << 4);
      const char* src = (const char*)(Abuf + (size_t)(rowBase + row) * KA + k0) + scol;
      gload16(src, sA + i*4096 + wid*1024);
    }
    // ---- stage B tile ----
    if constexpr (WB16){
      #pragma unroll
      for (int i = 0; i < 4; ++i){
        int flat = i*4096 + wid*1024 + lane*16;
        int row  = flat >> 7;
        int colb = flat & 127;
        int scol = colb ^ ((row & 7) << 4);
        const char* src = (const char*)(Wb + (Wrow0 + row) * KA + k0) + scol;
        gload16(src, sB + i*4096 + wid*1024);
      }
    } else {
      // reg-stage fp32 -> bf16, write-side swizzle
      #pragma unroll
      for (int i = 0; i < 8; ++i){
        int f4  = i*256 + tid;
        int row = f4 >> 4;
        int c4  = f4 & 15;
        float4 v = *reinterpret_cast<const float4*>(Wf + (Wrow0 + row) * KA + k0 + c4*4);
        uint2 p;
        p.x = f2bf(v.x) | (f2bf(v.y) << 16);
        p.y = f2bf(v.z) | (f2bf(v.w) << 16);
        int byte = row*128 + c4*8;
        *reinterpret_cast<uint2*>(sB + (byte ^ ((row & 7) << 4))) = p;
      }
    }
    __syncthreads();
    // ---- compute (swapped operands: each thread holds 4 contiguous output cols) ----
    #pragma unroll
    for (int ks = 0; ks < 2; ++ks){
      short8 a[4], b[4];
      #pragma unroll
      for (int m = 0; m < 4; ++m){
        int row = wr*64 + m*16 + lr;
        a[m] = *reinterpret_cast<const short8*>(sA + row*128 + ((ks*64 + lg*16) ^ ((row & 7) << 4)));
      }
      #pragma unroll
      for (int n = 0; n < 4; ++n){
        int row = wc*64 + n*16 + lr;
        b[n] = *reinterpret_cast<const short8*>(sB + row*128 + ((ks*64 + lg*16) ^ ((row & 7) << 4)));
      }
      #pragma unroll
      for (int m = 0; m < 4; ++m)
        #pragma unroll
        for (int n = 0; n < 4; ++n)
          acc[m][n] = __builtin_amdgcn_mfma_f32_16x16x32_bf16(b[n], a[m], acc[m][n], 0, 0, 0);
    }
    __syncthreads();
  }

  // epilogue: rows rowBase+wr*64+m*16+lr ; cols nBase+wc*64+n*16+lg*4+{0..3}
  int colBase = nBase + wc*64;
  if constexpr (PH1){
    #pragma unroll
    for (int n = 0; n < 4; ++n){
      int gc = colBase + n*16 + lg*4;
      float4 b4 = *reinterpret_cast<const float4*>(bias + (size_t)e*F_ + gc);
      #pragma unroll
      for (int m = 0; m < 4; ++m){
        int gr = rowBase + wr*64 + m*16 + lr;
        uint2 p;
        p.x = f2bf(gelu_f(acc[m][n][0] + b4.x)) | (f2bf(gelu_f(acc[m][n][1] + b4.y)) << 16);
        p.y = f2bf(gelu_f(acc[m][n][2] + b4.z)) | (f2bf(gelu_f(acc[m][n][3] + b4.w)) << 16);
        *reinterpret_cast<uint2*>(Out16 + (size_t)gr * F_ + gc) = p;
      }
    }
  } else {
    #pragma unroll
    for (int n = 0; n < 4; ++n){
      int gc = colBase + n*16 + lg*4;
      #pragma unroll
      for (int m = 0; m < 4; ++m){
        int gr = rowBase + wr*64 + m*16 + lr;
        uint2 p;
        p.x = f2bf(acc[m][n][0]) | (f2bf(acc[m][n][1]) << 16);
        p.y = f2bf(acc[m][n][2]) | (f2bf(acc[m][n][3]) << 16);
        *reinterpret_cast<uint2*>(Out16 + (size_t)gr * D_ + gc) = p;
      }
    }
  }
}

extern "C" void kernel_launch(void* const* d_in, const int* in_sizes, int n_in,
                              void* d_out, int out_size, void* d_ws, size_t ws_size,
                              hipStream_t stream){
  const float* x   = (const float*)d_in[0];
  const float* gw  = (const float*)d_in[1];
  const float* wfc = (const float*)d_in[2];
  const float* bfc = (const float*)d_in[3];
  const float* wpj = (const float*)d_in[4];
  const float* bpj = (const float*)d_in[5];
  float* out = (float*)d_out;

  int T = in_sizes[0] / D_;               // 8192
  int nAssign = T * K_;
  int nSlotsMax = nAssign + E_ * ALIGN_;  // 17408
  int rowTiles = nSlotsMax / 128;         // 136

  char* ws = (char*)d_ws;
  size_t o = 0;
  int*   tidx    = (int*)(ws + o); o += (size_t)nAssign * 4;
  float* tw      = (float*)(ws + o); o += (size_t)nAssign * 4;
  int*   counts  = (int*)(ws + o); o += 256;
  int*   tokSlot = (int*)(ws + o); o += (size_t)nAssign * 4;
  o = (o + 255) & ~(size_t)255;

  size_t abytes = (size_t)nSlotsMax * D_ * 2;   // Abuf; reused as Ybuf after GEMM1
  size_t hbytes = (size_t)nSlotsMax * F_ * 2;
  size_t wbytes = (size_t)E_ * F_ * D_ * 2;

  __hip_bfloat16* Abuf = (__hip_bfloat16*)(ws + o); o += abytes;
  __hip_bfloat16* Hbuf = (__hip_bfloat16*)(ws + o); o += hbytes;
  size_t o_w = o;
  __hip_bfloat16* wA = (__hip_bfloat16*)(ws + o_w);
  __hip_bfloat16* wB = (__hip_bfloat16*)(ws + o_w + wbytes);

  // x16: token-ordered bf16 copy of x, live only between gate and scatgath.
  // Aliases the FRONT of Hbuf (34 MB < 143 MB): GEMM1's Hbuf writes are stream-ordered
  // after scatgath's x16 reads, so no overlap hazard and no ws growth.
  unsigned short* x16 = (unsigned short*)Hbuf;

  bool newPath = (ws_size >= o_w + 2*wbytes);   // both weights upfront
  bool midPath = (ws_size >= o_w + wbytes);     // one buffer, serial reuse

  int n4 = E_ * F_ * D_ / 4;
  int nwg1 = (F_/128) * rowTiles;   // 4352, %8==0
  int nwg2 = (D_/128) * rowTiles;   // 1088, %8==0
  int gateBlocks = (T + 3)/4;       // 2048
  unsigned short* Ybuf = (unsigned short*)Abuf;

  if (newPath){
    // gate + cvt(wfc) co-scheduled; GEMM1 + cvt(wpj) co-scheduled
    gatecvt_kernel<<<gateBlocks + 2048, 256, 0, stream>>>(
        x, gw, tidx, tw, x16, T, wfc, wA, n4, gateBlocks);
    slotscan_kernel<<<1, 256, 0, stream>>>(tidx, counts, tokSlot, nAssign);
    scatgath_kernel<<<T, 128, 0, stream>>>(x16, tokSlot, Abuf);
    gemm_kernel<true, true><<<nwg1 + 2048, 256, 0, stream>>>(
        Abuf, (const void*)wA, bfc, counts, (unsigned short*)Hbuf, wpj, wB, n4, nwg1);
    gemm_kernel<true, false><<<nwg2, 256, 0, stream>>>(
        Hbuf, (const void*)wB, bpj, counts, Ybuf, nullptr, nullptr, 0, nwg2);
    combine_kernel<<<T, 256, 0, stream>>>(Ybuf, tidx, tw, tokSlot, bpj, out);
  } else if (midPath){
    gatecvt_kernel<<<gateBlocks + 2048, 256, 0, stream>>>(
        x, gw, tidx, tw, x16, T, wfc, wA, n4, gateBlocks);
    slotscan_kernel<<<1, 256, 0, stream>>>(tidx, counts, tokSlot, nAssign);
    scatgath_kernel<<<T, 128, 0, stream>>>(x16, tokSlot, Abuf);
    gemm_kernel<true, true><<<nwg1, 256, 0, stream>>>(
        Abuf, (const void*)wA, bfc, counts, (unsigned short*)Hbuf, nullptr, nullptr, 0, nwg1);
    cvtw_kernel<<<2048, 256, 0, stream>>>(wpj, wA, n4);
    gemm_kernel<true, false><<<nwg2, 256, 0, stream>>>(
        Hbuf, (const void*)wA, bpj, counts, Ybuf, nullptr, nullptr, 0, nwg2);
    combine_kernel<<<T, 256, 0, stream>>>(Ybuf, tidx, tw, tokSlot, bpj, out);
  } else {
    gatecvt_kernel<<<gateBlocks, 256, 0, stream>>>(
        x, gw, tidx, tw, x16, T, nullptr, nullptr, 0, gateBlocks);
    slotscan_kernel<<<1, 256, 0, stream>>>(tidx, counts, tokSlot, nAssign);
    scatgath_kernel<<<T, 128, 0, stream>>>(x16, tokSlot, Abuf);
    gemm_kernel<false, true><<<nwg1, 256, 0, stream>>>(
        Abuf, (const void*)wfc, bfc, counts, (unsigned short*)Hbuf, nullptr, nullptr, 0, nwg1);
    gemm_kernel<false, false><<<nwg2, 256, 0, stream>>>(
        Hbuf, (const void*)wpj, bpj, counts, Ybuf, nullptr, nullptr, 0, nwg2);
    combine_kernel<<<T, 256, 0, stream>>>(Ybuf, tidx, tw, tokSlot, bpj, out);
  }
}

// Round 14
// 503.141 us; speedup vs baseline: 1.1326x; 1.0070x over previous
//
#include <hip/hip_runtime.h>
#include <hip/hip_bf16.h>

#define E_ 8
#define D_ 1024
#define F_ 4096
#define K_ 2
#define ALIGN_ 128

typedef __attribute__((ext_vector_type(8))) short short8;
typedef __attribute__((ext_vector_type(4))) float f32x4;

__device__ __forceinline__ unsigned f2bf(float f){
  union { __hip_bfloat16 h; unsigned short u; } c;
  c.h = __float2bfloat16(f);
  return (unsigned)c.u;
}

__device__ __forceinline__ float bf2f(unsigned u){
  union { float f; unsigned u; } c;
  c.u = u << 16;
  return c.f;
}

__device__ __forceinline__ float gelu_f(float v){
  const float c0 = 0.7978845608028654f;   // sqrt(2/pi)
  float z = c0 * (v + 0.044715f * v * v * v);
  float e = __expf(2.0f * z);
  float t = 1.0f - 2.0f / (1.0f + e);     // tanh(z), stable for |z| large
  return 0.5f * v * (1.0f + t);
}

__device__ __forceinline__ void gload16(const void* gsrc, void* ldst){
  __builtin_amdgcn_global_load_lds(
      (const __attribute__((address_space(1))) unsigned int*)gsrc,
      (__attribute__((address_space(3))) unsigned int*)ldst, 16, 0, 0);
}

// grid-stride fp32 -> bf16 conversion over n4 float4 groups (blockDim must be 256).
// NON-TEMPORAL loads: the fp32 weight source is read exactly once — keeping it out of
// L2/LLC stops the co-scheduled cvt from evicting the GEMM's H/A/B panels
// (R13: GEMM2 FETCH 178->520 MB, dur 195->219 us from this pollution).
__device__ __forceinline__ void cvt_range(const float* __restrict__ src,
                                          __hip_bfloat16* __restrict__ dst,
                                          int n4, int cb, int nCvt){
  size_t stride = (size_t)nCvt * 256;
  for (size_t i = (size_t)cb*256 + threadIdx.x; i < (size_t)n4; i += stride){
#if __has_builtin(__builtin_nontemporal_load)
    f32x4 v = __builtin_nontemporal_load(reinterpret_cast<const f32x4*>(src) + i);
#else
    f32x4 v = reinterpret_cast<const f32x4*>(src)[i];
#endif
    uint2 p;
    p.x = f2bf(v[0]) | (f2bf(v[1]) << 16);
    p.y = f2bf(v[2]) | (f2bf(v[3]) << 16);
    reinterpret_cast<uint2*>(dst)[i] = p;   // store stays cached: next GEMM reads it
  }
}

// ---------------- gating: top-2 + softmax + bf16 x copy; tail blocks convert wfc ----------------
__global__ void gatecvt_kernel(const float* __restrict__ x, const float* __restrict__ gw,
                               int* __restrict__ tidx, float* __restrict__ tw,
                               unsigned short* __restrict__ x16, int T,
                               const float* __restrict__ csrc, __hip_bfloat16* __restrict__ cdst,
                               int n4, int gateBlocks){
  if ((int)blockIdx.x >= gateBlocks){
    cvt_range(csrc, cdst, n4, blockIdx.x - gateBlocks, gridDim.x - gateBlocks);
    return;
  }
  int wid = threadIdx.x >> 6, lane = threadIdx.x & 63;
  int t = blockIdx.x * 4 + wid;
  if (t >= T) return;
  const float4* xr = reinterpret_cast<const float4*>(x + (size_t)t * D_);
  uint2* x16r = reinterpret_cast<uint2*>(x16 + (size_t)t * D_);
  double acc[E_];
  #pragma unroll
  for (int e = 0; e < E_; ++e) acc[e] = 0.0;
  #pragma unroll
  for (int j = 0; j < 4; ++j){
    float4 xv = xr[j*64 + lane];
    uint2 p;
    p.x = f2bf(xv.x) | (f2bf(xv.y) << 16);
    p.y = f2bf(xv.z) | (f2bf(xv.w) << 16);
    x16r[j*64 + lane] = p;                 // bf16 copy for scatgath
    #pragma unroll
    for (int e = 0; e < E_; ++e){
      float4 wv = *reinterpret_cast<const float4*>(gw + (size_t)e*D_ + (j*64 + lane)*4);
      acc[e] += (double)xv.x*wv.x + (double)xv.y*wv.y + (double)xv.z*wv.z + (double)xv.w*wv.w;
    }
  }
  #pragma unroll
  for (int e = 0; e < E_; ++e){
    #pragma unroll
    for (int off = 32; off >= 1; off >>= 1)
      acc[e] += __shfl_xor(acc[e], off);
  }
  if (lane == 0){
    float l[E_];
    #pragma unroll
    for (int e = 0; e < E_; ++e) l[e] = (float)acc[e];
    int i0 = 0; float v0 = l[0];
    #pragma unroll
    for (int e = 1; e < E_; ++e) if (l[e] > v0){ v0 = l[e]; i0 = e; }
    int i1 = -1; float v1 = -1e30f;
    #pragma unroll
    for (int e = 0; e < E_; ++e) if (e != i0 && l[e] > v1){ v1 = l[e]; i1 = e; }
    float e1 = expf(v1 - v0);
    float s = 1.0f + e1;
    tidx[2*t] = i0; tidx[2*t+1] = i1;
    tw[2*t] = 1.0f / s; tw[2*t+1] = e1 / s;
  }
}

// ---------------- slot scan: deterministic histogram + prefix, single block ----------------
__global__ void slotscan_kernel(const int* __restrict__ tidx, int* __restrict__ counts,
                                int* __restrict__ tokSlot, int nAssign){
  __shared__ int cnt[256][E_];
  __shared__ int wtot[E_][4];
  __shared__ int ebase[E_];
  const int tid = threadIdx.x;
  const int lane = tid & 63, w = tid >> 6;
  const int per = (nAssign + 255) >> 8;
  const int base = tid * per;

  #pragma unroll
  for (int e = 0; e < E_; ++e) cnt[tid][e] = 0;
  for (int j = 0; j < per; ++j){
    int i = base + j;
    if (i < nAssign) cnt[tid][tidx[i]]++;
  }
  int excl[E_];
  #pragma unroll
  for (int e = 0; e < E_; ++e){
    int v = cnt[tid][e];
    int s = v;
    #pragma unroll
    for (int off = 1; off < 64; off <<= 1){
      int u = __shfl_up(s, off);
      if (lane >= off) s += u;
    }
    if (lane == 63) wtot[e][w] = s;
    excl[e] = s - v;
  }
  __syncthreads();
  if (tid == 0){
    int pre = 0;
    #pragma unroll
    for (int e = 0; e < E_; ++e){
      int tot = 0;
      #pragma unroll
      for (int ww = 0; ww < 4; ++ww){ int c = wtot[e][ww]; wtot[e][ww] = tot; tot += c; }
      counts[e] = tot;
      ebase[e] = pre;
      pre += (tot + (ALIGN_-1)) & ~(ALIGN_-1);
    }
  }
  __syncthreads();
  #pragma unroll
  for (int e = 0; e < E_; ++e)
    cnt[tid][e] = ebase[e] + wtot[e][w] + excl[e];
  for (int j = 0; j < per; ++j){
    int i = base + j;
    if (i < nAssign){
      int e = tidx[i];
      tokSlot[i] = cnt[tid][e]++;
    }
  }
}

// ---------------- gather: bf16 row copy (from x16) to precomputed slots ----------------
__global__ void scatgath_kernel(const unsigned short* __restrict__ x16,
                                const int* __restrict__ tokSlot,
                                __hip_bfloat16* __restrict__ Abuf){
  int t = blockIdx.x;
  int s0 = tokSlot[K_*t], s1 = tokSlot[K_*t + 1];
  uint4 p = *(reinterpret_cast<const uint4*>(x16 + (size_t)t * D_) + threadIdx.x);
  *(reinterpret_cast<uint4*>(reinterpret_cast<unsigned short*>(Abuf) + (size_t)s0*D_) + threadIdx.x) = p;
  *(reinterpret_cast<uint4*>(reinterpret_cast<unsigned short*>(Abuf) + (size_t)s1*D_) + threadIdx.x) = p;
}

// ---------------- standalone weight cvt (midPath / fallback) ----------------
__global__ void cvtw_kernel(const float* __restrict__ src, __hip_bfloat16* __restrict__ dst, int n4){
  cvt_range(src, dst, n4, blockIdx.x, gridDim.x);
}

// ---------------- combine: out[t] = sum_k w_k * (Y[slot_k] + b_proj[e_k]) ----------------
__global__ void combine_kernel(const unsigned short* __restrict__ Ybuf,
                               const int* __restrict__ tidx, const float* __restrict__ tw,
                               const int* __restrict__ tokSlot,
                               const float* __restrict__ bpj,
                               float* __restrict__ out){
  int t = blockIdx.x;
  int d = threadIdx.x * 4;
  int e0 = tidx[2*t], e1 = tidx[2*t+1];
  float w0 = tw[2*t], w1 = tw[2*t+1];
  int s0 = tokSlot[2*t], s1 = tokSlot[2*t+1];
  uint2 ya = *reinterpret_cast<const uint2*>(Ybuf + (size_t)s0*D_ + d);
  uint2 yb = *reinterpret_cast<const uint2*>(Ybuf + (size_t)s1*D_ + d);
  float4 b0 = *reinterpret_cast<const float4*>(bpj + (size_t)e0*D_ + d);
  float4 b1 = *reinterpret_cast<const float4*>(bpj + (size_t)e1*D_ + d);
  float4 r;
  r.x = w0*(bf2f(ya.x & 0xffffu) + b0.x) + w1*(bf2f(yb.x & 0xffffu) + b1.x);
  r.y = w0*(bf2f(ya.x >> 16)     + b0.y) + w1*(bf2f(yb.x >> 16)     + b1.y);
  r.z = w0*(bf2f(ya.y & 0xffffu) + b0.z) + w1*(bf2f(yb.y & 0xffffu) + b1.z);
  r.w = w0*(bf2f(ya.y >> 16)     + b0.w) + w1*(bf2f(yb.y >> 16)     + b1.w);
  *reinterpret_cast<float4*>(out + (size_t)t*D_ + d) = r;
}

// ---------------- 128x128 GEMM (m97 structure + XCD ROW-chunk swizzle; 4 blocks/CU) ----------------
// PH1: H = gelu(A wfc^T + b) -> bf16 Hbuf[slot][F]
// PH2: Y = H wproj^T         -> bf16 Ybuf[slot][D]   (bias+route applied in combine)
// Tail blocks (blockIdx >= nwgGemm) run a grid-stride fp32->bf16 weight conversion,
// co-scheduled in GEMM1's spare BW (GEMM1 runs at only ~54% of achievable HBM BW).
// NOTE: __launch_bounds__ min-waves MUST stay 4: acc[4][4] needs 64 VGPRs;
// (256,5) capped VGPR at 48 -> accumulator spilled to scratch (R8: WRITE_SIZE 1.1 GB, 2x slower).
// NOTE: grid mapping MUST be row-chunk (columns fastest within an XCD chunk): the XCD's
// concurrent A working set stays ~1 MB (L2-resident). Column-slab ordering (R10) re-streamed
// A per column tile: FETCH 448->581 MB, dur 196->220 us. Keep xt (columns) fastest.
template<bool WB16, bool PH1>
__global__ __launch_bounds__(256, 4) void gemm_kernel(
    const __hip_bfloat16* __restrict__ Abuf,   // [rows][KA] bf16
    const void* __restrict__ W,                // [E][NT][KA] bf16 or fp32
    const float* __restrict__ bias,            // [E][NT] (PH1 only)
    const int* __restrict__ counts,
    unsigned short* __restrict__ Out16,
    const float* __restrict__ csrc,            // optional tail-block cvt
    __hip_bfloat16* __restrict__ cdst,
    int n4, int nwgGemm)
{
  constexpr int KA = PH1 ? D_ : F_;
  constexpr int NT = PH1 ? F_ : D_;
  constexpr int NK = KA / 64;
  constexpr int NX = NT / 128;

  __shared__ char sA[128*128];   // 16 KB
  __shared__ char sB[128*128];   // 16 KB

  if ((int)blockIdx.x >= nwgGemm){
    cvt_range(csrc, cdst, n4, blockIdx.x - nwgGemm, gridDim.x - nwgGemm);
    return;
  }

  int pre[E_]; int total = 0;
  #pragma unroll
  for (int i = 0; i < E_; ++i){ pre[i] = total; total += (counts[i] + (ALIGN_-1)) & ~(ALIGN_-1); }

  // bijective XCD row-chunk swizzle over the GEMM sub-grid (nwgGemm % 8 == 0)
  int q = nwgGemm >> 3;
  int wgid = (blockIdx.x & 7) * q + (blockIdx.x >> 3);
  int yt = wgid / NX, xt = wgid - yt*NX;         // xt (columns) fastest
  int rowBase = yt * 128;
  if (rowBase >= total) return;
  int e = 0;
  #pragma unroll
  for (int i = 1; i < E_; ++i) if (rowBase >= pre[i]) e = i;
  int nBase = xt * 128;

  const int tid = threadIdx.x;
  const int wid = tid >> 6, lane = tid & 63;
  const int lr = lane & 15, lg = lane >> 4;
  const int wr = wid >> 1, wc = wid & 1;

  const unsigned short* Wb = (const unsigned short*)W;
  const float* Wf = (const float*)W;
  const size_t Wrow0 = (size_t)e * NT + nBase;

  f32x4 acc[4][4];
  #pragma unroll
  for (int m = 0; m < 4; ++m)
    #pragma unroll
    for (int n = 0; n < 4; ++n) acc[m][n] = (f32x4){0.f,0.f,0.f,0.f};

  for (int kt = 0; kt < NK; ++kt){
    int k0 = kt * 64;
    // ---- stage A tile via global_load_lds (linear dest, inverse-swizzled source) ----
    #pragma unroll
    for (int i = 0; i < 4; ++i){
      int flat = i*4096 + wid*1024 + lane*16;
      int row  = flat >> 7;
      int colb = flat & 127;
      int scol = colb ^ ((row & 7) << 4);
      const char* src = (const char*)(Abuf + (size_t)(rowBase + row) * KA + k0) + scol;
      gload16(src, sA + i*4096 + wid*1024);
    }
    // ---- stage B tile ----
    if constexpr (WB16){
      #pragma unroll
      for (int i = 0; i < 4; ++i){
        int flat = i*4096 + wid*1024 + lane*16;
        int row  = flat >> 7;
        int colb = flat & 127;
        int scol = colb ^ ((row & 7) << 4);
        const char* src = (const char*)(Wb + (Wrow0 + row) * KA + k0) + scol;
        gload16(src, sB + i*4096 + wid*1024);
      }
    } else {
      // reg-stage fp32 -> bf16, write-side swizzle
      #pragma unroll
      for (int i = 0; i < 8; ++i){
        int f4  = i*256 + tid;
        int row = f4 >> 4;
        int c4  = f4 & 15;
        float4 v = *reinterpret_cast<const float4*>(Wf + (Wrow0 + row) * KA + k0 + c4*4);
        uint2 p;
        p.x = f2bf(v.x) | (f2bf(v.y) << 16);
        p.y = f2bf(v.z) | (f2bf(v.w) << 16);
        int byte = row*128 + c4*8;
        *reinterpret_cast<uint2*>(sB + (byte ^ ((row & 7) << 4))) = p;
      }
    }
    __syncthreads();
    // ---- compute (swapped operands: each thread holds 4 contiguous output cols) ----
    #pragma unroll
    for (int ks = 0; ks < 2; ++ks){
      short8 a[4], b[4];
      #pragma unroll
      for (int m = 0; m < 4; ++m){
        int row = wr*64 + m*16 + lr;
        a[m] = *reinterpret_cast<const short8*>(sA + row*128 + ((ks*64 + lg*16) ^ ((row & 7) << 4)));
      }
      #pragma unroll
      for (int n = 0; n < 4; ++n){
        int row = wc*64 + n*16 + lr;
        b[n] = *reinterpret_cast<const short8*>(sB + row*128 + ((ks*64 + lg*16) ^ ((row & 7) << 4)));
      }
      #pragma unroll
      for (int m = 0; m < 4; ++m)
        #pragma unroll
        for (int n = 0; n < 4; ++n)
          acc[m][n] = __builtin_amdgcn_mfma_f32_16x16x32_bf16(b[n], a[m], acc[m][n], 0, 0, 0);
    }
    __syncthreads();
  }

  // epilogue: rows rowBase+wr*64+m*16+lr ; cols nBase+wc*64+n*16+lg*4+{0..3}
  int colBase = nBase + wc*64;
  if constexpr (PH1){
    #pragma unroll
    for (int n = 0; n < 4; ++n){
      int gc = colBase + n*16 + lg*4;
      float4 b4 = *reinterpret_cast<const float4*>(bias + (size_t)e*F_ + gc);
      #pragma unroll
      for (int m = 0; m < 4; ++m){
        int gr = rowBase + wr*64 + m*16 + lr;
        uint2 p;
        p.x = f2bf(gelu_f(acc[m][n][0] + b4.x)) | (f2bf(gelu_f(acc[m][n][1] + b4.y)) << 16);
        p.y = f2bf(gelu_f(acc[m][n][2] + b4.z)) | (f2bf(gelu_f(acc[m][n][3] + b4.w)) << 16);
        *reinterpret_cast<uint2*>(Out16 + (size_t)gr * F_ + gc) = p;
      }
    }
  } else {
    #pragma unroll
    for (int n = 0; n < 4; ++n){
      int gc = colBase + n*16 + lg*4;
      #pragma unroll
      for (int m = 0; m < 4; ++m){
        int gr = rowBase + wr*64 + m*16 + lr;
        uint2 p;
        p.x = f2bf(acc[m][n][0]) | (f2bf(acc[m][n][1]) << 16);
        p.y = f2bf(acc[m][n][2]) | (f2bf(acc[m][n][3]) << 16);
        *reinterpret_cast<uint2*>(Out16 + (size_t)gr * D_ + gc) = p;
      }
    }
  }
}

extern "C" void kernel_launch(void* const* d_in, const int* in_sizes, int n_in,
                              void* d_out, int out_size, void* d_ws, size_t ws_size,
                              hipStream_t stream){
  const float* x   = (const float*)d_in[0];
  const float* gw  = (const float*)d_in[1];
  const float* wfc = (const float*)d_in[2];
  const float* bfc = (const float*)d_in[3];
  const float* wpj = (const float*)d_in[4];
  const float* bpj = (const float*)d_in[5];
  float* out = (float*)d_out;

  int T = in_sizes[0] / D_;               // 8192
  int nAssign = T * K_;
  int nSlotsMax = nAssign + E_ * ALIGN_;  // 17408
  int rowTiles = nSlotsMax / 128;         // 136

  char* ws = (char*)d_ws;
  size_t o = 0;
  int*   tidx    = (int*)(ws + o); o += (size_t)nAssign * 4;
  float* tw      = (float*)(ws + o); o += (size_t)nAssign * 4;
  int*   counts  = (int*)(ws + o); o += 256;
  int*   tokSlot = (int*)(ws + o); o += (size_t)nAssign * 4;
  o = (o + 255) & ~(size_t)255;

  size_t abytes = (size_t)nSlotsMax * D_ * 2;   // Abuf; reused as Ybuf after GEMM1
  size_t hbytes = (size_t)nSlotsMax * F_ * 2;
  size_t wbytes = (size_t)E_ * F_ * D_ * 2;

  __hip_bfloat16* Abuf = (__hip_bfloat16*)(ws + o); o += abytes;
  __hip_bfloat16* Hbuf = (__hip_bfloat16*)(ws + o); o += hbytes;
  size_t o_w = o;
  __hip_bfloat16* wA = (__hip_bfloat16*)(ws + o_w);
  __hip_bfloat16* wB = (__hip_bfloat16*)(ws + o_w + wbytes);

  // x16: token-ordered bf16 copy of x, live only between gate and scatgath.
  // Aliases the FRONT of Hbuf (34 MB < 143 MB): GEMM1's Hbuf writes are stream-ordered
  // after scatgath's x16 reads, so no overlap hazard and no ws growth.
  unsigned short* x16 = (unsigned short*)Hbuf;

  bool newPath = (ws_size >= o_w + 2*wbytes);   // both weights upfront
  bool midPath = (ws_size >= o_w + wbytes);     // one buffer, serial reuse

  int n4 = E_ * F_ * D_ / 4;
  int nwg1 = (F_/128) * rowTiles;   // 4352, %8==0
  int nwg2 = (D_/128) * rowTiles;   // 1088, %8==0
  int gateBlocks = (T + 3)/4;       // 2048
  unsigned short* Ybuf = (unsigned short*)Abuf;

  if (newPath){
    // gate + cvt(wfc) co-scheduled; GEMM1 + cvt(wpj) co-scheduled
    gatecvt_kernel<<<gateBlocks + 2048, 256, 0, stream>>>(
        x, gw, tidx, tw, x16, T, wfc, wA, n4, gateBlocks);
    slotscan_kernel<<<1, 256, 0, stream>>>(tidx, counts, tokSlot, nAssign);
    scatgath_kernel<<<T, 128, 0, stream>>>(x16, tokSlot, Abuf);
    gemm_kernel<true, true><<<nwg1 + 2048, 256, 0, stream>>>(
        Abuf, (const void*)wA, bfc, counts, (unsigned short*)Hbuf, wpj, wB, n4, nwg1);
    gemm_kernel<true, false><<<nwg2, 256, 0, stream>>>(
        Hbuf, (const void*)wB, bpj, counts, Ybuf, nullptr, nullptr, 0, nwg2);
    combine_kernel<<<T, 256, 0, stream>>>(Ybuf, tidx, tw, tokSlot, bpj, out);
  } else if (midPath){
    gatecvt_kernel<<<gateBlocks + 2048, 256, 0, stream>>>(
        x, gw, tidx, tw, x16, T, wfc, wA, n4, gateBlocks);
    slotscan_kernel<<<1, 256, 0, stream>>>(tidx, counts, tokSlot, nAssign);
    scatgath_kernel<<<T, 128, 0, stream>>>(x16, tokSlot, Abuf);
    gemm_kernel<true, true><<<nwg1, 256, 0, stream>>>(
        Abuf, (const void*)wA, bfc, counts, (unsigned short*)Hbuf, nullptr, nullptr, 0, nwg1);
    cvtw_kernel<<<2048, 256, 0, stream>>>(wpj, wA, n4);
    gemm_kernel<true, false><<<nwg2, 256, 0, stream>>>(
        Hbuf, (const void*)wA, bpj, counts, Ybuf, nullptr, nullptr, 0, nwg2);
    combine_kernel<<<T, 256, 0, stream>>>(Ybuf, tidx, tw, tokSlot, bpj, out);
  } else {
    gatecvt_kernel<<<gateBlocks, 256, 0, stream>>>(
        x, gw, tidx, tw, x16, T, nullptr, nullptr, 0, gateBlocks);
    slotscan_kernel<<<1, 256, 0, stream>>>(tidx, counts, tokSlot, nAssign);
    scatgath_kernel<<<T, 128, 0, stream>>>(x16, tokSlot, Abuf);
    gemm_kernel<false, true><<<nwg1, 256, 0, stream>>>(
        Abuf, (const void*)wfc, bfc, counts, (unsigned short*)Hbuf, nullptr, nullptr, 0, nwg1);
    gemm_kernel<false, false><<<nwg2, 256, 0, stream>>>(
        Hbuf, (const void*)wpj, bpj, counts, Ybuf, nullptr, nullptr, 0, nwg2);
    combine_kernel<<<T, 256, 0, stream>>>(Ybuf, tidx, tw, tokSlot, bpj, out);
  }
}